// Round 3
// baseline (238.699 us; speedup 1.0000x reference)
//
#include <hip/hip_runtime.h>

typedef __bf16 bf16;
typedef __attribute__((ext_vector_type(8))) __bf16 bf16x8;
typedef __attribute__((ext_vector_type(4))) __bf16 bf16x4;
typedef __attribute__((ext_vector_type(4))) float f32x4;

__device__ __forceinline__ void gload16(const void* g, void* l) {
  __builtin_amdgcn_global_load_lds(
      (__attribute__((address_space(1))) void*)(g),
      (__attribute__((address_space(3))) void*)(l), 16, 0, 0);
}

// ---------------------------------------------------------------------------
// Workspace layout (bytes):
//   xh  : NHWC padded input, bf16 [130][130][512]        = 17,305,600
//   w1t : conv1 weights,     bf16 [9][512 oc][512 c]     =  4,718,592
//   w2p : packed head wts,   bf16 [80 oc2][512 c]        =     81,920
//   mid : conv1 output NHWC, bf16 [16384 px][512 oc]     = 16,777,216
// ---------------------------------------------------------------------------
#define WS_XH   0
#define WS_W1T  17305600
#define WS_W2P  22024192
#define WS_MID  22106112

#define OUT_CLS 786432
#define OUT_ROI 1179648

// ---------------- fused prep: border | w1 repack | w2 pack | transpose -----
// grid = 132 + 1024 + 160 + 2048 = 3364 blocks, 256 thr    (unchanged)
__global__ void prep_all(int4* __restrict__ xh4,
                         const float* __restrict__ w1, bf16* __restrict__ w1t,
                         const float* __restrict__ loc_w,
                         const float* __restrict__ score_w,
                         bf16* __restrict__ w2p,
                         const float* __restrict__ x, bf16* __restrict__ xh) {
  __shared__ float lds[64][65];
  float* ldsf = &lds[0][0];
  const int t = threadIdx.x;
  const int b = blockIdx.x;
  if (b < 132) {                       // ---- xh halo border zeroing
    const int4 z = make_int4(0, 0, 0, 0);
    if (b < 130) {
      if (t < 64)       xh4[(b * 130 + 0) * 64 + t] = z;
      else if (t < 128) xh4[(b * 130 + 129) * 64 + (t - 64)] = z;
    } else {
      const int r = (b == 130) ? 0 : 129;
      for (int i = t; i < 8320; i += 256) xh4[r * 8320 + i] = z;
    }
  } else if (b < 1156) {               // ---- w1 [oc][c][3][3] -> w1t[j][oc][c]
    const int bb = b - 132;
    const long base = (long)bb * 2304;
#pragma unroll
    for (int i = 0; i < 9; ++i) ldsf[i * 256 + t] = w1[base + i * 256 + t];
    __syncthreads();
    const int pair0 = bb * 256;        // pair = oc*512 + c
#pragma unroll
    for (int j = 0; j < 9; ++j)
      w1t[(long)j * 262144 + pair0 + t] = (bf16)ldsf[t * 9 + j];
  } else if (b < 1316) {               // ---- pack loc_w+score_w -> w2p[80][512]
    const int idx = (b - 1156) * 256 + t;
    const int c  = idx & 511;
    const int oc = idx >> 9;
    float v = 0.f;
    if (oc < 48)      v = loc_w[oc * 512 + c];
    else if (oc < 72) v = score_w[(oc - 48) * 512 + c];
    w2p[idx] = (bf16)v;
  } else {                             // ---- NCHW fp32 -> NHWC bf16 transpose
    const int bb   = b - 1316;
    const int ct   = bb & 7;
    const int colt = (bb >> 3) & 1;
    const int r    = 1 + (bb >> 4);
    const int c0   = ct * 64;
    const int col0 = 1 + colt * 64;
    const int lcol = t & 63;
    const int coff = t >> 6;
#pragma unroll
    for (int i = 0; i < 16; ++i) {
      const int cl = coff + i * 4;
      lds[cl][lcol] = x[(long)(c0 + cl) * 16384 + (r - 1) * 128 + (col0 - 1) + lcol];
    }
    __syncthreads();
#pragma unroll
    for (int i = 0; i < 2; ++i) {
      const int idx = i * 256 + t;
      const int pxl = idx >> 3;
      const int oct = idx & 7;
      bf16x8 v;
#pragma unroll
      for (int e = 0; e < 8; ++e) v[e] = (bf16)lds[oct * 8 + e][pxl];
      *(bf16x8*)(xh + (long)(r * 130 + col0 + pxl) * 512 + c0 + oct * 8) = v;
    }
  }
}

// ---------------- conv1 implicit GEMM: prefetched-fragment pipeline --------
// R2 retried: the pipeline schedule (A staged 3 ahead, B pong certified at
// j=8, fragments for subslot t+1 read during t) is unchanged and was
// verified correct; the R2 implementation spilled because fragment arrays
// were passed by pointer into lambdas across "memory"-clobber asm -> allocas
// never promoted (WRITE_SIZE 16->37MB, VGPR stuck at 128, 1st-dispatch
// scratch-alloc stall). This version uses 16 NAMED bf16x8 registers and
// macro-expanded reads/MFMAs: no arrays, no address escape, pure SSA.
__global__ __launch_bounds__(512, 2) void conv1_gemm(
    const bf16* __restrict__ w1t, const bf16* __restrict__ xh,
    const float* __restrict__ b1, bf16* __restrict__ mid) {
  extern __shared__ char smem[];
  // layout: B ping [784 rows][64B] @ 0 ; B pong @ 50176 ; A ring 4x4KB @ 100352
  char* Bb0 = smem;
  char* Bb1 = smem + 50176;
  char* Ab  = smem + 100352;

  const int tid  = threadIdx.x;
  const int wave = tid >> 6;
  const int lane = tid & 63;
  const int quad = lane >> 4;
  const int l15  = lane & 15;
  const int b    = blockIdx.x;
  const int ocT  = b & 7;          // XCD-affine: same ocT -> same XCD L2
  const int r4   = b >> 3;         // 4-image-row px tile, 0..31
  const long rbase = (long)r4 * 520;        // 4*130 xh rows per tile

  const char* w1tB = (const char*)w1t + (long)ocT * 65536;
  const char* xhB  = (const char*)xh;

  const int srow = lane >> 2;                               // 16 rows/unit
  const int schk = ((lane & 3) ^ ((lane >> 3) & 3)) << 4;   // src chunk swizzle

  // stage 1KB unit of A(tap j, col ck): wave w (0..3) stages rows [w*16,+16)
  auto stageA = [&](int ck, int j, int slot) {
    const char* src = w1tB + (long)j * 524288 +
                      (long)(wave * 16 + srow) * 1024 + ck * 64 + schk;
    gload16(src, Ab + slot * 4096 + wave * 1024);
  };
  // stage 1KB unit u (16 xh rows) of the B window at column ck
  auto stageB = [&](int ck, int u, char* Bt) {
    const char* src = xhB + (rbase + u * 16 + srow) * 1024 + ck * 64 + schk;
    gload16(src, Bt + u * 1024);
  };

  // per-wave B row bases: px p = wave*64 + ni*16 + l15 ->
  // local row = (p>>7)*130 + (p&127) + l15  (+ ky*130 + kx at use)
  const int p0 = wave * 64;
  const int rowb0 = (((p0 + 0)  >> 7) * 130) + ((p0 + 0)  & 127) + l15;
  const int rowb1 = (((p0 + 16) >> 7) * 130) + ((p0 + 16) & 127) + l15;
  const int rowb2 = (((p0 + 32) >> 7) * 130) + ((p0 + 32) & 127) + l15;
  const int rowb3 = (((p0 + 48) >> 7) * 130) + ((p0 + 48) & 127) + l15;
  const int aoff = l15 * 64 + ((quad ^ ((l15 >> 1) & 3)) << 4);

  f32x4 acc[4][4];
#pragma unroll
  for (int i = 0; i < 4; ++i)
#pragma unroll
    for (int k = 0; k < 4; ++k) acc[i][k] = (f32x4){0.f, 0.f, 0.f, 0.f};

  // current / next fragment sets: individually named, no arrays
  bf16x8 ca0, ca1, ca2, ca3, cb0, cb1, cb2, cb3;
  bf16x8 na0, na1, na2, na3, nb0, nb1, nb2, nb3;

#define BROW(R, BT) (*(const bf16x8*)((BT) + (R) * 64 + ((quad ^ (((R) >> 1) & 3)) << 4)))
#define READF(A0, A1, A2, A3, B0, B1, B2, B3, slot, koff, BT)                 \
  do {                                                                        \
    const char* _ab = Ab + (slot) * 4096 + aoff;                              \
    A0 = *(const bf16x8*)(_ab);                                               \
    A1 = *(const bf16x8*)(_ab + 1024);                                        \
    A2 = *(const bf16x8*)(_ab + 2048);                                        \
    A3 = *(const bf16x8*)(_ab + 3072);                                        \
    const int _r0 = rowb0 + (koff);                                           \
    const int _r1 = rowb1 + (koff);                                           \
    const int _r2 = rowb2 + (koff);                                           \
    const int _r3 = rowb3 + (koff);                                           \
    B0 = BROW(_r0, BT); B1 = BROW(_r1, BT);                                   \
    B2 = BROW(_r2, BT); B3 = BROW(_r3, BT);                                   \
  } while (0)
#define MF(MI, NI, AF, BF)                                                    \
  acc[MI][NI] = __builtin_amdgcn_mfma_f32_16x16x32_bf16(AF, BF, acc[MI][NI], 0, 0, 0)
#define DOMFMA()                                                              \
  do {                                                                        \
    __builtin_amdgcn_s_setprio(1);                                            \
    MF(0, 0, ca0, cb0); MF(0, 1, ca0, cb1); MF(0, 2, ca0, cb2); MF(0, 3, ca0, cb3); \
    MF(1, 0, ca1, cb0); MF(1, 1, ca1, cb1); MF(1, 2, ca1, cb2); MF(1, 3, ca1, cb3); \
    MF(2, 0, ca2, cb0); MF(2, 1, ca2, cb1); MF(2, 2, ca2, cb2); MF(2, 3, ca2, cb3); \
    MF(3, 0, ca3, cb0); MF(3, 1, ca3, cb1); MF(3, 2, ca3, cb2); MF(3, 3, ca3, cb3); \
    __builtin_amdgcn_s_setprio(0);                                            \
  } while (0)
#define ROT()                                                                 \
  do {                                                                        \
    ca0 = na0; ca1 = na1; ca2 = na2; ca3 = na3;                               \
    cb0 = nb0; cb1 = nb1; cb2 = nb2; cb3 = nb3;                               \
  } while (0)

#define KOFF(J) (((J) / 3) * 130 + ((J) % 3))
#define WAITA1 asm volatile("s_waitcnt vmcnt(1)" ::: "memory")
#define WAIT0  asm volatile("s_waitcnt vmcnt(0)" ::: "memory")
#define BARR   __builtin_amdgcn_s_barrier()
#define SCHEDB __builtin_amdgcn_sched_barrier(0)

  // prologue: B(0) fully; A tiles for t=0,1,2 into ring slots 0,1,2
  if (wave < 4) {
    stageA(0, 0, 0);
    stageA(0, 1, 1);
    stageA(0, 2, 2);
    asm volatile("s_waitcnt vmcnt(2)" ::: "memory");   // slot 0 landed
  } else {
    const int u0 = (wave == 4) ? 0 : 13 + (wave - 5) * 12;
    const int n  = (wave == 4) ? 13 : 12;
    for (int u = 0; u < n; ++u) stageB(0, u0 + u, Bb0);
    WAIT0;
  }
  BARR;
  READF(ca0, ca1, ca2, ca3, cb0, cb1, cb2, cb3, 0, KOFF(0), Bb0);  // frags t=0

  for (int s = 0; s < 15; ++s) {
    char* Bcur = (s & 1) ? Bb1 : Bb0;
    char* Bnxt = (s & 1) ? Bb0 : Bb1;
#pragma unroll
    for (int j = 0; j < 9; ++j) {
      if (wave < 4) { WAITA1; }
      else if (j == 8) { WAIT0; }        // pong fully landed for early read
      BARR;
      const int t = s * 9 + j;
      if (wave < 4) {                    // A staging: 3 subslots ahead
        if (j < 6) stageA(s, j + 3, (t + 3) & 3);
        else       stageA(s + 1, j - 6, (t + 3) & 3);
      } else if (j < 6) {                // B(ck+1): ~2 units/subslot
        int u0, n;
        if (wave == 4) { n = (j == 0) ? 3 : 2; u0 = (j == 0) ? 0 : 3 + (j - 1) * 2; }
        else           { n = 2; u0 = 13 + (wave - 5) * 12 + j * 2; }
        for (int u = 0; u < n; ++u) stageB(s + 1, u0 + u, Bnxt);
      }
      // prefetch fragments for t+1 (issue before MFMA; no dependency)
      if (j < 8) READF(na0, na1, na2, na3, nb0, nb1, nb2, nb3,
                       (t + 1) & 3, KOFF(j + 1), Bcur);
      else       READF(na0, na1, na2, na3, nb0, nb1, nb2, nb3,
                       (t + 1) & 3, KOFF(0), Bnxt);
      SCHEDB;
      DOMFMA();                          // uses frags read at t-1
      ROT();
    }
  }
  { // s = 15 peel: no B staging, exact A drain, no read past t=143
    const int s = 15;
    char* Bcur = Bb1;
#pragma unroll
    for (int j = 0; j < 9; ++j) {
      const int t = 135 + j;
      if (wave < 4) {
        if (j <= 6) { WAITA1; }
        else if (j == 7) { WAIT0; }
      }
      BARR;
      if (wave < 4 && j < 6) stageA(s, j + 3, (t + 3) & 3);
      if (j < 8) READF(na0, na1, na2, na3, nb0, nb1, nb2, nb3,
                       (t + 1) & 3, KOFF(j + 1), Bcur);
      SCHEDB;
      DOMFMA();
      if (j < 8) { ROT(); }
    }
  }

#undef KOFF
#undef WAITA1
#undef WAIT0
#undef BARR
#undef SCHEDB
#undef BROW
#undef READF
#undef MF
#undef DOMFMA
#undef ROT

  // epilogue: bias + relu, store bf16 NHWC mid[px][oc]
#pragma unroll
  for (int mi = 0; mi < 4; ++mi) {
    const int oc = ocT * 64 + mi * 16 + quad * 4;
    const float bv0 = b1[oc], bv1 = b1[oc + 1], bv2 = b1[oc + 2], bv3 = b1[oc + 3];
#pragma unroll
    for (int ni = 0; ni < 4; ++ni) {
      const int pb  = p0 + ni * 16;
      const int gpx = (r4 * 4 + (pb >> 7)) * 128 + (pb & 127) + l15;
      f32x4 a = acc[mi][ni];
      float t0 = a[0] + bv0; t0 = t0 > 0.f ? t0 : 0.f;
      float t1 = a[1] + bv1; t1 = t1 > 0.f ? t1 : 0.f;
      float t2 = a[2] + bv2; t2 = t2 > 0.f ? t2 : 0.f;
      float t3 = a[3] + bv3; t3 = t3 > 0.f ? t3 : 0.f;
      bf16x4 v = {(bf16)t0, (bf16)t1, (bf16)t2, (bf16)t3};
      *(bf16x4*)(mid + (long)gpx * 512 + oc) = v;
    }
  }
}

// ---------------- head: barrier-free K-split GEMM + anchor decode ----------
__global__ __launch_bounds__(256) void head_gemm(
    const bf16* __restrict__ w2p, const bf16* __restrict__ mid,
    const float* __restrict__ loc_b, const float* __restrict__ score_b,
    float* __restrict__ out) {
  __shared__ f32x4 red[3][64][5];
  const int tid  = threadIdx.x;
  const int wave = tid >> 6;
  const int lane = tid & 63;
  const int quad = lane >> 4;
  const int l15  = lane & 15;
  const int px0  = blockIdx.x * 16;
  const bf16* mB = mid + (long)px0 * 512;

  f32x4 acc[5];
#pragma unroll
  for (int i = 0; i < 5; ++i) acc[i] = (f32x4){0.f, 0.f, 0.f, 0.f};

#pragma unroll
  for (int st = 0; st < 4; ++st) {
    const int k0 = wave * 128 + st * 32;
    bf16x8 bfr = *(const bf16x8*)(mB + (long)l15 * 512 + k0 + quad * 8);
#pragma unroll
    for (int mi = 0; mi < 5; ++mi) {
      bf16x8 af = *(const bf16x8*)(w2p + (long)(mi * 16 + l15) * 512 + k0 + quad * 8);
      acc[mi] = __builtin_amdgcn_mfma_f32_16x16x32_bf16(af, bfr, acc[mi], 0, 0, 0);
    }
  }

  if (wave > 0) {
#pragma unroll
    for (int mi = 0; mi < 5; ++mi) red[wave - 1][lane][mi] = acc[mi];
  }
  __syncthreads();
  if (wave != 0) return;
#pragma unroll
  for (int w = 0; w < 3; ++w)
#pragma unroll
    for (int mi = 0; mi < 5; ++mi) acc[mi] += red[w][lane][mi];

  const int p    = px0 + l15;
  const int hh   = p >> 7;
  const int wcol = p & 127;
  const float cx = 16.f * (float)hh;
  const float cy = 16.f * (float)wcol;
  const float s0 = quad == 0 ? 45.f : quad == 1 ? 91.f : quad == 2 ? 181.f : 362.f;
  const float s1 = quad == 0 ? 32.f : quad == 1 ? 64.f : quad == 2 ? 128.f : 256.f;
  const float s2 = quad == 0 ? 23.f : quad == 1 ? 45.f : quad == 2 ? 91.f : 181.f;
  const float aw[3] = {s0, s1, s2};
  const float ah[3] = {s2, s1, s0};
#pragma unroll
  for (int mi = 0; mi < 5; ++mi) {
#pragma unroll
    for (int r = 0; r < 4; ++r) {
      const int oc2 = mi * 16 + quad * 4 + r;
      float v = acc[mi][r];
      if (mi < 3) {
        v += loc_b[oc2];
        out[p * 48 + oc2] = v;
        float roi;
        if (r == 0)      roi = v * aw[mi] + cx;
        else if (r == 1) roi = v * ah[mi] + cy;
        else if (r == 2) roi = __expf(v) * aw[mi];
        else             roi = __expf(v) * ah[mi];
        out[OUT_ROI + p * 48 + oc2] = roi;
      } else {
        const int sc = oc2 - 48;
        if (sc < 24) {
          v += score_b[sc];
          out[OUT_CLS + p * 24 + sc] = v;
        }
      }
    }
  }
}

// ---------------------------------------------------------------------------
extern "C" void kernel_launch(void* const* d_in, const int* in_sizes, int n_in,
                              void* d_out, int out_size, void* d_ws, size_t ws_size,
                              hipStream_t stream) {
  (void)in_sizes; (void)n_in; (void)out_size; (void)ws_size;
  const float* x       = (const float*)d_in[0];
  const float* conv1_w = (const float*)d_in[1];
  const float* conv1_b = (const float*)d_in[2];
  const float* score_w = (const float*)d_in[3];
  const float* score_b = (const float*)d_in[4];
  const float* loc_w   = (const float*)d_in[5];
  const float* loc_b   = (const float*)d_in[6];
  char* ws = (char*)d_ws;
  bf16* xh  = (bf16*)(ws + WS_XH);
  bf16* w1t = (bf16*)(ws + WS_W1T);
  bf16* w2p = (bf16*)(ws + WS_W2P);
  bf16* mid = (bf16*)(ws + WS_MID);
  float* out = (float*)d_out;

  static int attr_done = 0;
  if (!attr_done) {
    (void)hipFuncSetAttribute((const void*)conv1_gemm,
                              hipFuncAttributeMaxDynamicSharedMemorySize, 116736);
    attr_done = 1;
  }

  hipLaunchKernelGGL(prep_all,   dim3(3364), dim3(256), 0, stream,
                     (int4*)xh, conv1_w, w1t, loc_w, score_w, w2p, x, xh);
  hipLaunchKernelGGL(conv1_gemm, dim3(256),  dim3(512), 116736, stream,
                     w1t, xh, conv1_b, mid);
  hipLaunchKernelGGL(head_gemm,  dim3(1024), dim3(256), 0, stream,
                     w2p, mid, loc_b, score_b, out);
}

// Round 4
// 236.627 us; speedup vs baseline: 1.0088x; 1.0088x over previous
//
#include <hip/hip_runtime.h>

typedef __bf16 bf16;
typedef __attribute__((ext_vector_type(8))) __bf16 bf16x8;
typedef __attribute__((ext_vector_type(4))) __bf16 bf16x4;
typedef __attribute__((ext_vector_type(4))) float f32x4;

__device__ __forceinline__ void gload16(const void* g, void* l) {
  __builtin_amdgcn_global_load_lds(
      (__attribute__((address_space(1))) void*)(g),
      (__attribute__((address_space(3))) void*)(l), 16, 0, 0);
}

// ---------------------------------------------------------------------------
// Workspace layout (bytes):
//   xh  : NHWC padded input, bf16 [130][130][512]        = 17,305,600
//   w1t : conv1 weights,     bf16 [9][512 oc][512 c]     =  4,718,592
//   w2p : packed head wts,   bf16 [80 oc2][512 c]        =     81,920
//   mid : conv1 output NHWC, bf16 [16384 px][512 oc]     = 16,777,216
// ---------------------------------------------------------------------------
#define WS_XH   0
#define WS_W1T  17305600
#define WS_W2P  22024192
#define WS_MID  22106112

#define OUT_CLS 786432
#define OUT_ROI 1179648

// ---------------- fused prep: border | w1 repack | w2 pack | transpose -----
// grid = 132 + 1024 + 160 + 2048 = 3364 blocks, 256 thr    (unchanged)
__global__ void prep_all(int4* __restrict__ xh4,
                         const float* __restrict__ w1, bf16* __restrict__ w1t,
                         const float* __restrict__ loc_w,
                         const float* __restrict__ score_w,
                         bf16* __restrict__ w2p,
                         const float* __restrict__ x, bf16* __restrict__ xh) {
  __shared__ float lds[64][65];
  float* ldsf = &lds[0][0];
  const int t = threadIdx.x;
  const int b = blockIdx.x;
  if (b < 132) {                       // ---- xh halo border zeroing
    const int4 z = make_int4(0, 0, 0, 0);
    if (b < 130) {
      if (t < 64)       xh4[(b * 130 + 0) * 64 + t] = z;
      else if (t < 128) xh4[(b * 130 + 129) * 64 + (t - 64)] = z;
    } else {
      const int r = (b == 130) ? 0 : 129;
      for (int i = t; i < 8320; i += 256) xh4[r * 8320 + i] = z;
    }
  } else if (b < 1156) {               // ---- w1 [oc][c][3][3] -> w1t[j][oc][c]
    const int bb = b - 132;
    const long base = (long)bb * 2304;
#pragma unroll
    for (int i = 0; i < 9; ++i) ldsf[i * 256 + t] = w1[base + i * 256 + t];
    __syncthreads();
    const int pair0 = bb * 256;        // pair = oc*512 + c
#pragma unroll
    for (int j = 0; j < 9; ++j)
      w1t[(long)j * 262144 + pair0 + t] = (bf16)ldsf[t * 9 + j];
  } else if (b < 1316) {               // ---- pack loc_w+score_w -> w2p[80][512]
    const int idx = (b - 1156) * 256 + t;
    const int c  = idx & 511;
    const int oc = idx >> 9;
    float v = 0.f;
    if (oc < 48)      v = loc_w[oc * 512 + c];
    else if (oc < 72) v = score_w[(oc - 48) * 512 + c];
    w2p[idx] = (bf16)v;
  } else {                             // ---- NCHW fp32 -> NHWC bf16 transpose
    const int bb   = b - 1316;
    const int ct   = bb & 7;
    const int colt = (bb >> 3) & 1;
    const int r    = 1 + (bb >> 4);
    const int c0   = ct * 64;
    const int col0 = 1 + colt * 64;
    const int lcol = t & 63;
    const int coff = t >> 6;
#pragma unroll
    for (int i = 0; i < 16; ++i) {
      const int cl = coff + i * 4;
      lds[cl][lcol] = x[(long)(c0 + cl) * 16384 + (r - 1) * 128 + (col0 - 1) + lcol];
    }
    __syncthreads();
#pragma unroll
    for (int i = 0; i < 2; ++i) {
      const int idx = i * 256 + t;
      const int pxl = idx >> 3;
      const int oct = idx & 7;
      bf16x8 v;
#pragma unroll
      for (int e = 0; e < 8; ++e) v[e] = (bf16)lds[oct * 8 + e][pxl];
      *(bf16x8*)(xh + (long)(r * 130 + col0 + pxl) * 512 + c0 + oct * 8) = v;
    }
  }
}

// ---------------- conv1 implicit GEMM: prefetched-fragment pipeline --------
// R3 post-mortem: VGPR_Count pinned at EXACTLY 128 with heavy scratch
// (WRITE 16->38MB) in both R2 and R3 regardless of source form -> the
// spill was a hard regalloc cap, not address-escape. Cause:
// __launch_bounds__(512, 2) is interpreted CUDA-style (2 blocks/CU ->
// 4 waves/SIMD -> 128-VGPR cap) for this 512-thread kernel. Occupancy is
// LDS-bound at 1 block/CU (117KB) anyway, so arg2=2 bought nothing.
// Fix: __launch_bounds__(512, 1) -> 256-VGPR cap; the ~190-reg working
// set (acc 64 + 16 named bf16x8 frags 64 + addressing) now fits.
// Pipeline (unchanged from R3, verified correct): A staged 3 ahead
// (ring-4), B pong certified at j=8, fragments for subslot t+1 read
// during t so MFMA(t) has no same-subslot lgkm dependency -> LDS-read
// burst (~768cy/CU) overlaps MFMA burst (~620cy/SIMD).
__global__ __launch_bounds__(512, 1) void conv1_gemm(
    const bf16* __restrict__ w1t, const bf16* __restrict__ xh,
    const float* __restrict__ b1, bf16* __restrict__ mid) {
  extern __shared__ char smem[];
  // layout: B ping [784 rows][64B] @ 0 ; B pong @ 50176 ; A ring 4x4KB @ 100352
  char* Bb0 = smem;
  char* Bb1 = smem + 50176;
  char* Ab  = smem + 100352;

  const int tid  = threadIdx.x;
  const int wave = tid >> 6;
  const int lane = tid & 63;
  const int quad = lane >> 4;
  const int l15  = lane & 15;
  const int b    = blockIdx.x;
  const int ocT  = b & 7;          // XCD-affine: same ocT -> same XCD L2
  const int r4   = b >> 3;         // 4-image-row px tile, 0..31
  const long rbase = (long)r4 * 520;        // 4*130 xh rows per tile

  const char* w1tB = (const char*)w1t + (long)ocT * 65536;
  const char* xhB  = (const char*)xh;

  const int srow = lane >> 2;                               // 16 rows/unit
  const int schk = ((lane & 3) ^ ((lane >> 3) & 3)) << 4;   // src chunk swizzle

  // stage 1KB unit of A(tap j, col ck): wave w (0..3) stages rows [w*16,+16)
  auto stageA = [&](int ck, int j, int slot) {
    const char* src = w1tB + (long)j * 524288 +
                      (long)(wave * 16 + srow) * 1024 + ck * 64 + schk;
    gload16(src, Ab + slot * 4096 + wave * 1024);
  };
  // stage 1KB unit u (16 xh rows) of the B window at column ck
  auto stageB = [&](int ck, int u, char* Bt) {
    const char* src = xhB + (rbase + u * 16 + srow) * 1024 + ck * 64 + schk;
    gload16(src, Bt + u * 1024);
  };

  // per-wave B row bases: px p = wave*64 + ni*16 + l15 ->
  // local row = (p>>7)*130 + (p&127) + l15  (+ ky*130 + kx at use)
  const int p0 = wave * 64;
  const int rowb0 = (((p0 + 0)  >> 7) * 130) + ((p0 + 0)  & 127) + l15;
  const int rowb1 = (((p0 + 16) >> 7) * 130) + ((p0 + 16) & 127) + l15;
  const int rowb2 = (((p0 + 32) >> 7) * 130) + ((p0 + 32) & 127) + l15;
  const int rowb3 = (((p0 + 48) >> 7) * 130) + ((p0 + 48) & 127) + l15;
  const int aoff = l15 * 64 + ((quad ^ ((l15 >> 1) & 3)) << 4);

  f32x4 acc[4][4];
#pragma unroll
  for (int i = 0; i < 4; ++i)
#pragma unroll
    for (int k = 0; k < 4; ++k) acc[i][k] = (f32x4){0.f, 0.f, 0.f, 0.f};

  // current / next fragment sets: individually named, no arrays
  bf16x8 ca0, ca1, ca2, ca3, cb0, cb1, cb2, cb3;
  bf16x8 na0, na1, na2, na3, nb0, nb1, nb2, nb3;

#define BROW(R, BT) (*(const bf16x8*)((BT) + (R) * 64 + ((quad ^ (((R) >> 1) & 3)) << 4)))
#define READF(A0, A1, A2, A3, B0, B1, B2, B3, slot, koff, BT)                 \
  do {                                                                        \
    const char* _ab = Ab + (slot) * 4096 + aoff;                              \
    A0 = *(const bf16x8*)(_ab);                                               \
    A1 = *(const bf16x8*)(_ab + 1024);                                        \
    A2 = *(const bf16x8*)(_ab + 2048);                                        \
    A3 = *(const bf16x8*)(_ab + 3072);                                        \
    const int _r0 = rowb0 + (koff);                                           \
    const int _r1 = rowb1 + (koff);                                           \
    const int _r2 = rowb2 + (koff);                                           \
    const int _r3 = rowb3 + (koff);                                           \
    B0 = BROW(_r0, BT); B1 = BROW(_r1, BT);                                   \
    B2 = BROW(_r2, BT); B3 = BROW(_r3, BT);                                   \
  } while (0)
#define MF(MI, NI, AF, BF)                                                    \
  acc[MI][NI] = __builtin_amdgcn_mfma_f32_16x16x32_bf16(AF, BF, acc[MI][NI], 0, 0, 0)
#define DOMFMA()                                                              \
  do {                                                                        \
    __builtin_amdgcn_s_setprio(1);                                            \
    MF(0, 0, ca0, cb0); MF(0, 1, ca0, cb1); MF(0, 2, ca0, cb2); MF(0, 3, ca0, cb3); \
    MF(1, 0, ca1, cb0); MF(1, 1, ca1, cb1); MF(1, 2, ca1, cb2); MF(1, 3, ca1, cb3); \
    MF(2, 0, ca2, cb0); MF(2, 1, ca2, cb1); MF(2, 2, ca2, cb2); MF(2, 3, ca2, cb3); \
    MF(3, 0, ca3, cb0); MF(3, 1, ca3, cb1); MF(3, 2, ca3, cb2); MF(3, 3, ca3, cb3); \
    __builtin_amdgcn_s_setprio(0);                                            \
  } while (0)
#define ROT()                                                                 \
  do {                                                                        \
    ca0 = na0; ca1 = na1; ca2 = na2; ca3 = na3;                               \
    cb0 = nb0; cb1 = nb1; cb2 = nb2; cb3 = nb3;                               \
  } while (0)

#define KOFF(J) (((J) / 3) * 130 + ((J) % 3))
#define WAITA1 asm volatile("s_waitcnt vmcnt(1)" ::: "memory")
#define WAIT0  asm volatile("s_waitcnt vmcnt(0)" ::: "memory")
#define BARR   __builtin_amdgcn_s_barrier()
#define SCHEDB __builtin_amdgcn_sched_barrier(0)

  // prologue: B(0) fully; A tiles for t=0,1,2 into ring slots 0,1,2
  if (wave < 4) {
    stageA(0, 0, 0);
    stageA(0, 1, 1);
    stageA(0, 2, 2);
    asm volatile("s_waitcnt vmcnt(2)" ::: "memory");   // slot 0 landed
  } else {
    const int u0 = (wave == 4) ? 0 : 13 + (wave - 5) * 12;
    const int n  = (wave == 4) ? 13 : 12;
    for (int u = 0; u < n; ++u) stageB(0, u0 + u, Bb0);
    WAIT0;
  }
  BARR;
  READF(ca0, ca1, ca2, ca3, cb0, cb1, cb2, cb3, 0, KOFF(0), Bb0);  // frags t=0

  for (int s = 0; s < 15; ++s) {
    char* Bcur = (s & 1) ? Bb1 : Bb0;
    char* Bnxt = (s & 1) ? Bb0 : Bb1;
#pragma unroll
    for (int j = 0; j < 9; ++j) {
      if (wave < 4) { WAITA1; }
      else if (j == 8) { WAIT0; }        // pong fully landed for early read
      BARR;
      const int t = s * 9 + j;
      if (wave < 4) {                    // A staging: 3 subslots ahead
        if (j < 6) stageA(s, j + 3, (t + 3) & 3);
        else       stageA(s + 1, j - 6, (t + 3) & 3);
      } else if (j < 6) {                // B(ck+1): ~2 units/subslot
        int u0, n;
        if (wave == 4) { n = (j == 0) ? 3 : 2; u0 = (j == 0) ? 0 : 3 + (j - 1) * 2; }
        else           { n = 2; u0 = 13 + (wave - 5) * 12 + j * 2; }
        for (int u = 0; u < n; ++u) stageB(s + 1, u0 + u, Bnxt);
      }
      // prefetch fragments for t+1 (issue before MFMA; no dependency)
      if (j < 8) READF(na0, na1, na2, na3, nb0, nb1, nb2, nb3,
                       (t + 1) & 3, KOFF(j + 1), Bcur);
      else       READF(na0, na1, na2, na3, nb0, nb1, nb2, nb3,
                       (t + 1) & 3, KOFF(0), Bnxt);
      SCHEDB;
      DOMFMA();                          // uses frags read at t-1
      ROT();
    }
  }
  { // s = 15 peel: no B staging, exact A drain, no read past t=143
    const int s = 15;
    char* Bcur = Bb1;
#pragma unroll
    for (int j = 0; j < 9; ++j) {
      const int t = 135 + j;
      if (wave < 4) {
        if (j <= 6) { WAITA1; }
        else if (j == 7) { WAIT0; }
      }
      BARR;
      if (wave < 4 && j < 6) stageA(s, j + 3, (t + 3) & 3);
      if (j < 8) READF(na0, na1, na2, na3, nb0, nb1, nb2, nb3,
                       (t + 1) & 3, KOFF(j + 1), Bcur);
      SCHEDB;
      DOMFMA();
      if (j < 8) { ROT(); }
    }
  }

#undef KOFF
#undef WAITA1
#undef WAIT0
#undef BARR
#undef SCHEDB
#undef BROW
#undef READF
#undef MF
#undef DOMFMA
#undef ROT

  // epilogue: bias + relu, store bf16 NHWC mid[px][oc]
#pragma unroll
  for (int mi = 0; mi < 4; ++mi) {
    const int oc = ocT * 64 + mi * 16 + quad * 4;
    const float bv0 = b1[oc], bv1 = b1[oc + 1], bv2 = b1[oc + 2], bv3 = b1[oc + 3];
#pragma unroll
    for (int ni = 0; ni < 4; ++ni) {
      const int pb  = p0 + ni * 16;
      const int gpx = (r4 * 4 + (pb >> 7)) * 128 + (pb & 127) + l15;
      f32x4 a = acc[mi][ni];
      float t0 = a[0] + bv0; t0 = t0 > 0.f ? t0 : 0.f;
      float t1 = a[1] + bv1; t1 = t1 > 0.f ? t1 : 0.f;
      float t2 = a[2] + bv2; t2 = t2 > 0.f ? t2 : 0.f;
      float t3 = a[3] + bv3; t3 = t3 > 0.f ? t3 : 0.f;
      bf16x4 v = {(bf16)t0, (bf16)t1, (bf16)t2, (bf16)t3};
      *(bf16x4*)(mid + (long)gpx * 512 + oc) = v;
    }
  }
}

// ---------------- head: barrier-free K-split GEMM + anchor decode ----------
__global__ __launch_bounds__(256) void head_gemm(
    const bf16* __restrict__ w2p, const bf16* __restrict__ mid,
    const float* __restrict__ loc_b, const float* __restrict__ score_b,
    float* __restrict__ out) {
  __shared__ f32x4 red[3][64][5];
  const int tid  = threadIdx.x;
  const int wave = tid >> 6;
  const int lane = tid & 63;
  const int quad = lane >> 4;
  const int l15  = lane & 15;
  const int px0  = blockIdx.x * 16;
  const bf16* mB = mid + (long)px0 * 512;

  f32x4 acc[5];
#pragma unroll
  for (int i = 0; i < 5; ++i) acc[i] = (f32x4){0.f, 0.f, 0.f, 0.f};

#pragma unroll
  for (int st = 0; st < 4; ++st) {
    const int k0 = wave * 128 + st * 32;
    bf16x8 bfr = *(const bf16x8*)(mB + (long)l15 * 512 + k0 + quad * 8);
#pragma unroll
    for (int mi = 0; mi < 5; ++mi) {
      bf16x8 af = *(const bf16x8*)(w2p + (long)(mi * 16 + l15) * 512 + k0 + quad * 8);
      acc[mi] = __builtin_amdgcn_mfma_f32_16x16x32_bf16(af, bfr, acc[mi], 0, 0, 0);
    }
  }

  if (wave > 0) {
#pragma unroll
    for (int mi = 0; mi < 5; ++mi) red[wave - 1][lane][mi] = acc[mi];
  }
  __syncthreads();
  if (wave != 0) return;
#pragma unroll
  for (int w = 0; w < 3; ++w)
#pragma unroll
    for (int mi = 0; mi < 5; ++mi) acc[mi] += red[w][lane][mi];

  const int p    = px0 + l15;
  const int hh   = p >> 7;
  const int wcol = p & 127;
  const float cx = 16.f * (float)hh;
  const float cy = 16.f * (float)wcol;
  const float s0 = quad == 0 ? 45.f : quad == 1 ? 91.f : quad == 2 ? 181.f : 362.f;
  const float s1 = quad == 0 ? 32.f : quad == 1 ? 64.f : quad == 2 ? 128.f : 256.f;
  const float s2 = quad == 0 ? 23.f : quad == 1 ? 45.f : quad == 2 ? 91.f : 181.f;
  const float aw[3] = {s0, s1, s2};
  const float ah[3] = {s2, s1, s0};
#pragma unroll
  for (int mi = 0; mi < 5; ++mi) {
#pragma unroll
    for (int r = 0; r < 4; ++r) {
      const int oc2 = mi * 16 + quad * 4 + r;
      float v = acc[mi][r];
      if (mi < 3) {
        v += loc_b[oc2];
        out[p * 48 + oc2] = v;
        float roi;
        if (r == 0)      roi = v * aw[mi] + cx;
        else if (r == 1) roi = v * ah[mi] + cy;
        else if (r == 2) roi = __expf(v) * aw[mi];
        else             roi = __expf(v) * ah[mi];
        out[OUT_ROI + p * 48 + oc2] = roi;
      } else {
        const int sc = oc2 - 48;
        if (sc < 24) {
          v += score_b[sc];
          out[OUT_CLS + p * 24 + sc] = v;
        }
      }
    }
  }
}

// ---------------------------------------------------------------------------
extern "C" void kernel_launch(void* const* d_in, const int* in_sizes, int n_in,
                              void* d_out, int out_size, void* d_ws, size_t ws_size,
                              hipStream_t stream) {
  (void)in_sizes; (void)n_in; (void)out_size; (void)ws_size;
  const float* x       = (const float*)d_in[0];
  const float* conv1_w = (const float*)d_in[1];
  const float* conv1_b = (const float*)d_in[2];
  const float* score_w = (const float*)d_in[3];
  const float* score_b = (const float*)d_in[4];
  const float* loc_w   = (const float*)d_in[5];
  const float* loc_b   = (const float*)d_in[6];
  char* ws = (char*)d_ws;
  bf16* xh  = (bf16*)(ws + WS_XH);
  bf16* w1t = (bf16*)(ws + WS_W1T);
  bf16* w2p = (bf16*)(ws + WS_W2P);
  bf16* mid = (bf16*)(ws + WS_MID);
  float* out = (float*)d_out;

  static int attr_done = 0;
  if (!attr_done) {
    (void)hipFuncSetAttribute((const void*)conv1_gemm,
                              hipFuncAttributeMaxDynamicSharedMemorySize, 116736);
    attr_done = 1;
  }

  hipLaunchKernelGGL(prep_all,   dim3(3364), dim3(256), 0, stream,
                     (int4*)xh, conv1_w, w1t, loc_w, score_w, w2p, x, xh);
  hipLaunchKernelGGL(conv1_gemm, dim3(256),  dim3(512), 116736, stream,
                     w1t, xh, conv1_b, mid);
  hipLaunchKernelGGL(head_gemm,  dim3(1024), dim3(256), 0, stream,
                     w2p, mid, loc_b, score_b, out);
}

// Round 5
// 182.574 us; speedup vs baseline: 1.3074x; 1.2961x over previous
//
#include <hip/hip_runtime.h>

typedef __bf16 bf16;
typedef __attribute__((ext_vector_type(8))) __bf16 bf16x8;
typedef __attribute__((ext_vector_type(4))) __bf16 bf16x4;
typedef __attribute__((ext_vector_type(4))) float f32x4;

__device__ __forceinline__ void gload16(const void* g, void* l) {
  __builtin_amdgcn_global_load_lds(
      (__attribute__((address_space(1))) void*)(g),
      (__attribute__((address_space(3))) void*)(l), 16, 0, 0);
}

// ---------------------------------------------------------------------------
// Workspace layout (bytes):
//   xh  : NHWC padded input, bf16 [130][130][512]        = 17,305,600
//   w1t : conv1 weights,     bf16 [9][512 oc][512 c]     =  4,718,592
//   w2p : packed head wts,   bf16 [80 oc2][512 c]        =     81,920
//   mid : conv1 output NHWC, bf16 [16384 px][512 oc]     = 16,777,216
// ---------------------------------------------------------------------------
#define WS_XH   0
#define WS_W1T  17305600
#define WS_W2P  22024192
#define WS_MID  22106112

#define OUT_CLS 786432
#define OUT_ROI 1179648

// ---------------- fused prep: border | w1 repack | w2 pack | transpose -----
// grid = 132 + 1024 + 160 + 2048 = 3364 blocks, 256 thr    (unchanged)
__global__ void prep_all(int4* __restrict__ xh4,
                         const float* __restrict__ w1, bf16* __restrict__ w1t,
                         const float* __restrict__ loc_w,
                         const float* __restrict__ score_w,
                         bf16* __restrict__ w2p,
                         const float* __restrict__ x, bf16* __restrict__ xh) {
  __shared__ float lds[64][65];
  float* ldsf = &lds[0][0];
  const int t = threadIdx.x;
  const int b = blockIdx.x;
  if (b < 132) {                       // ---- xh halo border zeroing
    const int4 z = make_int4(0, 0, 0, 0);
    if (b < 130) {
      if (t < 64)       xh4[(b * 130 + 0) * 64 + t] = z;
      else if (t < 128) xh4[(b * 130 + 129) * 64 + (t - 64)] = z;
    } else {
      const int r = (b == 130) ? 0 : 129;
      for (int i = t; i < 8320; i += 256) xh4[r * 8320 + i] = z;
    }
  } else if (b < 1156) {               // ---- w1 [oc][c][3][3] -> w1t[j][oc][c]
    const int bb = b - 132;
    const long base = (long)bb * 2304;
#pragma unroll
    for (int i = 0; i < 9; ++i) ldsf[i * 256 + t] = w1[base + i * 256 + t];
    __syncthreads();
    const int pair0 = bb * 256;        // pair = oc*512 + c
#pragma unroll
    for (int j = 0; j < 9; ++j)
      w1t[(long)j * 262144 + pair0 + t] = (bf16)ldsf[t * 9 + j];
  } else if (b < 1316) {               // ---- pack loc_w+score_w -> w2p[80][512]
    const int idx = (b - 1156) * 256 + t;
    const int c  = idx & 511;
    const int oc = idx >> 9;
    float v = 0.f;
    if (oc < 48)      v = loc_w[oc * 512 + c];
    else if (oc < 72) v = score_w[(oc - 48) * 512 + c];
    w2p[idx] = (bf16)v;
  } else {                             // ---- NCHW fp32 -> NHWC bf16 transpose
    const int bb   = b - 1316;
    const int ct   = bb & 7;
    const int colt = (bb >> 3) & 1;
    const int r    = 1 + (bb >> 4);
    const int c0   = ct * 64;
    const int col0 = 1 + colt * 64;
    const int lcol = t & 63;
    const int coff = t >> 6;
#pragma unroll
    for (int i = 0; i < 16; ++i) {
      const int cl = coff + i * 4;
      lds[cl][lcol] = x[(long)(c0 + cl) * 16384 + (r - 1) * 128 + (col0 - 1) + lcol];
    }
    __syncthreads();
#pragma unroll
    for (int i = 0; i < 2; ++i) {
      const int idx = i * 256 + t;
      const int pxl = idx >> 3;
      const int oct = idx & 7;
      bf16x8 v;
#pragma unroll
      for (int e = 0; e < 8; ++e) v[e] = (bf16)lds[oct * 8 + e][pxl];
      *(bf16x8*)(xh + (long)(r * 130 + col0 + pxl) * 512 + c0 + oct * 8) = v;
    }
  }
}

// ---------------- conv1 implicit GEMM: group-barrier wave-staggered --------
// R2-R4 post-mortem: the allocator pins this kernel at 128 arch VGPRs
// (acc lives in the unified-file AGPR half); any fragment double-buffer
// (+64 regs) spills to scratch regardless of source form. So: no intra-wave
// prefetch. Instead remove the lockstep that serialized the pipes in R1
// (barrier every subslot => all 8 waves read, THEN all MFMA: 770cy LDS +
// 515cy MFMA back-to-back = 1368cy/subslot).
// This version barriers once per 3-subslot GROUP. Within a group waves
// free-run and self-stagger via the LDS queue: one wave's MFMA burst
// overlaps the others' ds_reads (m114 mechanism; zero extra registers;
// setprio now has wave role-diversity to arbitrate).
// Safety: A ring = one 4KB slot per tap j (9 slots); tap tiles for group
// g+2 staged during g (A-waves vmcnt(3) at each barrier: 2 batches in
// flight, drain oldest). Old slot content was last read in group g-1,
// before the barrier that precedes the overwrite. B ping/pong as before;
// pong certified by B-waves vmcnt(0) at superslot-boundary barriers.
// Compute per subslot = R1's proven in-subslot reads (128 VGPR, 0 scratch).
__global__ __launch_bounds__(512, 1) void conv1_gemm(
    const bf16* __restrict__ w1t, const bf16* __restrict__ xh,
    const float* __restrict__ b1, bf16* __restrict__ mid) {
  extern __shared__ char smem[];
  // B ping [784 rows][64B] @ 0 ; B pong @ 50176 ; A taps 9x4KB @ 100352
  char* Bb0 = smem;
  char* Bb1 = smem + 50176;
  char* Ab  = smem + 100352;          // total 137216 B

  const int tid  = threadIdx.x;
  const int wave = tid >> 6;
  const int lane = tid & 63;
  const int quad = lane >> 4;
  const int l15  = lane & 15;
  const int b    = blockIdx.x;
  const int ocT  = b & 7;          // XCD-affine: same ocT -> same XCD L2
  const int r4   = b >> 3;         // 4-image-row px tile, 0..31
  const long rbase = (long)r4 * 520;        // 4*130 xh rows per tile

  const char* w1tB = (const char*)w1t + (long)ocT * 65536;
  const char* xhB  = (const char*)xh;

  const int srow = lane >> 2;                               // 16 rows/unit
  const int schk = ((lane & 3) ^ ((lane >> 3) & 3)) << 4;   // src chunk swizzle

  // stage the 4KB A tile of (tap j, col ck) into slot j; waves 0-3 do 1KB each
  auto stageA = [&](int ck, int j) {
    const char* src = w1tB + (long)j * 524288 +
                      (long)(wave * 16 + srow) * 1024 + ck * 64 + schk;
    gload16(src, Ab + j * 4096 + wave * 1024);
  };
  // stage 1KB unit u (16 xh rows) of the B window at column ck
  auto stageB = [&](int ck, int u, char* Bt) {
    const char* src = xhB + (rbase + u * 16 + srow) * 1024 + ck * 64 + schk;
    gload16(src, Bt + u * 1024);
  };

  // per-wave B row bases: px p = wave*64 + ni*16 + l15 ->
  // local row = (p>>7)*130 + (p&127) + l15  (+ ky*130 + kx at use)
  const int p0 = wave * 64;
  const int rowb0 = (((p0 + 0)  >> 7) * 130) + ((p0 + 0)  & 127) + l15;
  const int rowb1 = (((p0 + 16) >> 7) * 130) + ((p0 + 16) & 127) + l15;
  const int rowb2 = (((p0 + 32) >> 7) * 130) + ((p0 + 32) & 127) + l15;
  const int rowb3 = (((p0 + 48) >> 7) * 130) + ((p0 + 48) & 127) + l15;
  const int aoff = l15 * 64 + ((quad ^ ((l15 >> 1) & 3)) << 4);

  f32x4 acc[4][4];
#pragma unroll
  for (int i = 0; i < 4; ++i)
#pragma unroll
    for (int k = 0; k < 4; ++k) acc[i][k] = (f32x4){0.f, 0.f, 0.f, 0.f};

  bf16x8 ca0, ca1, ca2, ca3, cb0, cb1, cb2, cb3;

#define BROW(R, BT) (*(const bf16x8*)((BT) + (R) * 64 + ((quad ^ (((R) >> 1) & 3)) << 4)))
#define READF(JSLOT, KO, BT)                                                  \
  do {                                                                        \
    const char* _ab = Ab + (JSLOT) * 4096 + aoff;                             \
    ca0 = *(const bf16x8*)(_ab);                                              \
    ca1 = *(const bf16x8*)(_ab + 1024);                                       \
    ca2 = *(const bf16x8*)(_ab + 2048);                                       \
    ca3 = *(const bf16x8*)(_ab + 3072);                                       \
    const int _r0 = rowb0 + (KO);                                             \
    const int _r1 = rowb1 + (KO);                                             \
    const int _r2 = rowb2 + (KO);                                             \
    const int _r3 = rowb3 + (KO);                                             \
    cb0 = BROW(_r0, BT); cb1 = BROW(_r1, BT);                                 \
    cb2 = BROW(_r2, BT); cb3 = BROW(_r3, BT);                                 \
  } while (0)
#define MF(MI, NI, AF, BF)                                                    \
  acc[MI][NI] = __builtin_amdgcn_mfma_f32_16x16x32_bf16(AF, BF, acc[MI][NI], 0, 0, 0)
#define DOMFMA()                                                              \
  do {                                                                        \
    __builtin_amdgcn_s_setprio(1);                                            \
    MF(0, 0, ca0, cb0); MF(0, 1, ca0, cb1); MF(0, 2, ca0, cb2); MF(0, 3, ca0, cb3); \
    MF(1, 0, ca1, cb0); MF(1, 1, ca1, cb1); MF(1, 2, ca1, cb2); MF(1, 3, ca1, cb3); \
    MF(2, 0, ca2, cb0); MF(2, 1, ca2, cb1); MF(2, 2, ca2, cb2); MF(2, 3, ca2, cb3); \
    MF(3, 0, ca3, cb0); MF(3, 1, ca3, cb1); MF(3, 2, ca3, cb2); MF(3, 3, ca3, cb3); \
    __builtin_amdgcn_s_setprio(0);                                            \
  } while (0)
// subslot I of the current group: tap j = 3q+I, koff = q*130+I, A slot = j
#define SUBSLOT(I, BT)                                                        \
  do { READF(3 * q + (I), q * 130 + (I), BT); DOMFMA(); } while (0)

#define WAITA3 asm volatile("s_waitcnt vmcnt(3)" ::: "memory")
#define WAIT0  asm volatile("s_waitcnt vmcnt(0)" ::: "memory")
#define BARR   __builtin_amdgcn_s_barrier()

  // prologue: B(0) fully; A taps 0-5 of ck=0 (groups 0 and 1's tiles)
  if (wave < 4) {
    stageA(0, 0); stageA(0, 1); stageA(0, 2);
    stageA(0, 3); stageA(0, 4); stageA(0, 5);
  } else {
    const int u0 = (wave == 4) ? 0 : 13 + (wave - 5) * 12;
    const int n  = (wave == 4) ? 13 : 12;
    for (int u = 0; u < n; ++u) stageB(0, u0 + u, Bb0);
  }

  // 48 groups of 3 subslots; group g: superslot s = g/3, phase q = g%3
  int s = 0, q = 0;
#pragma unroll 1
  for (int g = 0; g < 47; ++g) {
    if (wave < 4) { WAITA3; }           // drain oldest A batch (this group's)
    else if (q == 0) { WAIT0; }         // superslot boundary: pong landed
    BARR;
    char* Bcur = (s & 1) ? Bb1 : Bb0;
    char* Bnxt = (s & 1) ? Bb0 : Bb1;
    if (g <= 45) {
      if (wave < 4) {                   // stage group g+2's 3 A taps
        const int qs = (q + 2 >= 3) ? q - 1 : q + 2;   // (q+2)%3
        const int ss = s + (q >= 1 ? 1 : 0);
        stageA(ss, qs * 3); stageA(ss, qs * 3 + 1); stageA(ss, qs * 3 + 2);
      } else if (g <= 44) {             // stage ~1/3 of B(s+1)
        int n, uoff;
        if (wave == 4) { n = (q == 0) ? 5 : 4; uoff = (q == 0) ? 0 : (q == 1 ? 5 : 9); }
        else           { n = 4; uoff = 13 + (wave - 5) * 12 + q * 4; }
        for (int u = 0; u < n; ++u) stageB(s + 1, uoff + u, Bnxt);
      }
    }
    // 3 subslots, no barriers between: waves self-stagger, pipes overlap
    SUBSLOT(0, Bcur);
    SUBSLOT(1, Bcur);
    SUBSLOT(2, Bcur);
    ++q; if (q == 3) { q = 0; ++s; }
  }
  { // g = 47 peel: s=15, q=2; drain last A batch fully
    if (wave < 4) { WAIT0; }
    BARR;
    char* Bcur = Bb1;
    const int qq = 2;
    READF(3 * qq + 0, qq * 130 + 0, Bcur); DOMFMA();
    READF(3 * qq + 1, qq * 130 + 1, Bcur); DOMFMA();
    READF(3 * qq + 2, qq * 130 + 2, Bcur); DOMFMA();
  }

#undef WAITA3
#undef WAIT0
#undef BARR
#undef BROW
#undef READF
#undef MF
#undef DOMFMA
#undef SUBSLOT

  // epilogue: bias + relu, store bf16 NHWC mid[px][oc]
#pragma unroll
  for (int mi = 0; mi < 4; ++mi) {
    const int oc = ocT * 64 + mi * 16 + quad * 4;
    const float bv0 = b1[oc], bv1 = b1[oc + 1], bv2 = b1[oc + 2], bv3 = b1[oc + 3];
#pragma unroll
    for (int ni = 0; ni < 4; ++ni) {
      const int pb  = p0 + ni * 16;
      const int gpx = (r4 * 4 + (pb >> 7)) * 128 + (pb & 127) + l15;
      f32x4 a = acc[mi][ni];
      float t0 = a[0] + bv0; t0 = t0 > 0.f ? t0 : 0.f;
      float t1 = a[1] + bv1; t1 = t1 > 0.f ? t1 : 0.f;
      float t2 = a[2] + bv2; t2 = t2 > 0.f ? t2 : 0.f;
      float t3 = a[3] + bv3; t3 = t3 > 0.f ? t3 : 0.f;
      bf16x4 v = {(bf16)t0, (bf16)t1, (bf16)t2, (bf16)t3};
      *(bf16x4*)(mid + (long)gpx * 512 + oc) = v;
    }
  }
}

// ---------------- head: barrier-free K-split GEMM + anchor decode ----------
__global__ __launch_bounds__(256) void head_gemm(
    const bf16* __restrict__ w2p, const bf16* __restrict__ mid,
    const float* __restrict__ loc_b, const float* __restrict__ score_b,
    float* __restrict__ out) {
  __shared__ f32x4 red[3][64][5];
  const int tid  = threadIdx.x;
  const int wave = tid >> 6;
  const int lane = tid & 63;
  const int quad = lane >> 4;
  const int l15  = lane & 15;
  const int px0  = blockIdx.x * 16;
  const bf16* mB = mid + (long)px0 * 512;

  f32x4 acc[5];
#pragma unroll
  for (int i = 0; i < 5; ++i) acc[i] = (f32x4){0.f, 0.f, 0.f, 0.f};

#pragma unroll
  for (int st = 0; st < 4; ++st) {
    const int k0 = wave * 128 + st * 32;
    bf16x8 bfr = *(const bf16x8*)(mB + (long)l15 * 512 + k0 + quad * 8);
#pragma unroll
    for (int mi = 0; mi < 5; ++mi) {
      bf16x8 af = *(const bf16x8*)(w2p + (long)(mi * 16 + l15) * 512 + k0 + quad * 8);
      acc[mi] = __builtin_amdgcn_mfma_f32_16x16x32_bf16(af, bfr, acc[mi], 0, 0, 0);
    }
  }

  if (wave > 0) {
#pragma unroll
    for (int mi = 0; mi < 5; ++mi) red[wave - 1][lane][mi] = acc[mi];
  }
  __syncthreads();
  if (wave != 0) return;
#pragma unroll
  for (int w = 0; w < 3; ++w)
#pragma unroll
    for (int mi = 0; mi < 5; ++mi) acc[mi] += red[w][lane][mi];

  const int p    = px0 + l15;
  const int hh   = p >> 7;
  const int wcol = p & 127;
  const float cx = 16.f * (float)hh;
  const float cy = 16.f * (float)wcol;
  const float s0 = quad == 0 ? 45.f : quad == 1 ? 91.f : quad == 2 ? 181.f : 362.f;
  const float s1 = quad == 0 ? 32.f : quad == 1 ? 64.f : quad == 2 ? 128.f : 256.f;
  const float s2 = quad == 0 ? 23.f : quad == 1 ? 45.f : quad == 2 ? 91.f : 181.f;
  const float aw[3] = {s0, s1, s2};
  const float ah[3] = {s2, s1, s0};
#pragma unroll
  for (int mi = 0; mi < 5; ++mi) {
#pragma unroll
    for (int r = 0; r < 4; ++r) {
      const int oc2 = mi * 16 + quad * 4 + r;
      float v = acc[mi][r];
      if (mi < 3) {
        v += loc_b[oc2];
        out[p * 48 + oc2] = v;
        float roi;
        if (r == 0)      roi = v * aw[mi] + cx;
        else if (r == 1) roi = v * ah[mi] + cy;
        else if (r == 2) roi = __expf(v) * aw[mi];
        else             roi = __expf(v) * ah[mi];
        out[OUT_ROI + p * 48 + oc2] = roi;
      } else {
        const int sc = oc2 - 48;
        if (sc < 24) {
          v += score_b[sc];
          out[OUT_CLS + p * 24 + sc] = v;
        }
      }
    }
  }
}

// ---------------------------------------------------------------------------
extern "C" void kernel_launch(void* const* d_in, const int* in_sizes, int n_in,
                              void* d_out, int out_size, void* d_ws, size_t ws_size,
                              hipStream_t stream) {
  (void)in_sizes; (void)n_in; (void)out_size; (void)ws_size;
  const float* x       = (const float*)d_in[0];
  const float* conv1_w = (const float*)d_in[1];
  const float* conv1_b = (const float*)d_in[2];
  const float* score_w = (const float*)d_in[3];
  const float* score_b = (const float*)d_in[4];
  const float* loc_w   = (const float*)d_in[5];
  const float* loc_b   = (const float*)d_in[6];
  char* ws = (char*)d_ws;
  bf16* xh  = (bf16*)(ws + WS_XH);
  bf16* w1t = (bf16*)(ws + WS_W1T);
  bf16* w2p = (bf16*)(ws + WS_W2P);
  bf16* mid = (bf16*)(ws + WS_MID);
  float* out = (float*)d_out;

  static int attr_done = 0;
  if (!attr_done) {
    (void)hipFuncSetAttribute((const void*)conv1_gemm,
                              hipFuncAttributeMaxDynamicSharedMemorySize, 137216);
    attr_done = 1;
  }

  hipLaunchKernelGGL(prep_all,   dim3(3364), dim3(256), 0, stream,
                     (int4*)xh, conv1_w, w1t, loc_w, score_w, w2p, x, xh);
  hipLaunchKernelGGL(conv1_gemm, dim3(256),  dim3(512), 137216, stream,
                     w1t, xh, conv1_b, mid);
  hipLaunchKernelGGL(head_gemm,  dim3(1024), dim3(256), 0, stream,
                     w2p, mid, loc_b, score_b, out);
}

// Round 6
// 179.594 us; speedup vs baseline: 1.3291x; 1.0166x over previous
//
#include <hip/hip_runtime.h>

typedef __bf16 bf16;
typedef __attribute__((ext_vector_type(8))) __bf16 bf16x8;
typedef __attribute__((ext_vector_type(4))) __bf16 bf16x4;
typedef __attribute__((ext_vector_type(4))) float f32x4;

__device__ __forceinline__ void gload16(const void* g, void* l) {
  __builtin_amdgcn_global_load_lds(
      (__attribute__((address_space(1))) void*)(g),
      (__attribute__((address_space(3))) void*)(l), 16, 0, 0);
}

// ---------------------------------------------------------------------------
// Workspace layout (bytes):
//   xh  : NHWC padded input, bf16 [130][130][512]        = 17,305,600
//   w1t : conv1 weights,     bf16 [9][512 oc][512 c]     =  4,718,592
//   w2p : packed head wts,   bf16 [80 oc2][512 c]        =     81,920
//   mid : conv1 output NHWC, bf16 [16384 px][512 oc]     = 16,777,216
// ---------------------------------------------------------------------------
#define WS_XH   0
#define WS_W1T  17305600
#define WS_W2P  22024192
#define WS_MID  22106112

#define OUT_CLS 786432
#define OUT_ROI 1179648

// ---------------- fused prep: border | w1 repack | w2 pack | transpose -----
// grid = 132 + 1024 + 160 + 2048 = 3364 blocks, 256 thr    (unchanged)
__global__ void prep_all(int4* __restrict__ xh4,
                         const float* __restrict__ w1, bf16* __restrict__ w1t,
                         const float* __restrict__ loc_w,
                         const float* __restrict__ score_w,
                         bf16* __restrict__ w2p,
                         const float* __restrict__ x, bf16* __restrict__ xh) {
  __shared__ float lds[64][65];
  float* ldsf = &lds[0][0];
  const int t = threadIdx.x;
  const int b = blockIdx.x;
  if (b < 132) {                       // ---- xh halo border zeroing
    const int4 z = make_int4(0, 0, 0, 0);
    if (b < 130) {
      if (t < 64)       xh4[(b * 130 + 0) * 64 + t] = z;
      else if (t < 128) xh4[(b * 130 + 129) * 64 + (t - 64)] = z;
    } else {
      const int r = (b == 130) ? 0 : 129;
      for (int i = t; i < 8320; i += 256) xh4[r * 8320 + i] = z;
    }
  } else if (b < 1156) {               // ---- w1 [oc][c][3][3] -> w1t[j][oc][c]
    const int bb = b - 132;
    const long base = (long)bb * 2304;
#pragma unroll
    for (int i = 0; i < 9; ++i) ldsf[i * 256 + t] = w1[base + i * 256 + t];
    __syncthreads();
    const int pair0 = bb * 256;        // pair = oc*512 + c
#pragma unroll
    for (int j = 0; j < 9; ++j)
      w1t[(long)j * 262144 + pair0 + t] = (bf16)ldsf[t * 9 + j];
  } else if (b < 1316) {               // ---- pack loc_w+score_w -> w2p[80][512]
    const int idx = (b - 1156) * 256 + t;
    const int c  = idx & 511;
    const int oc = idx >> 9;
    float v = 0.f;
    if (oc < 48)      v = loc_w[oc * 512 + c];
    else if (oc < 72) v = score_w[(oc - 48) * 512 + c];
    w2p[idx] = (bf16)v;
  } else {                             // ---- NCHW fp32 -> NHWC bf16 transpose
    const int bb   = b - 1316;
    const int ct   = bb & 7;
    const int colt = (bb >> 3) & 1;
    const int r    = 1 + (bb >> 4);
    const int c0   = ct * 64;
    const int col0 = 1 + colt * 64;
    const int lcol = t & 63;
    const int coff = t >> 6;
#pragma unroll
    for (int i = 0; i < 16; ++i) {
      const int cl = coff + i * 4;
      lds[cl][lcol] = x[(long)(c0 + cl) * 16384 + (r - 1) * 128 + (col0 - 1) + lcol];
    }
    __syncthreads();
#pragma unroll
    for (int i = 0; i < 2; ++i) {
      const int idx = i * 256 + t;
      const int pxl = idx >> 3;
      const int oct = idx & 7;
      bf16x8 v;
#pragma unroll
      for (int e = 0; e < 8; ++e) v[e] = (bf16)lds[oct * 8 + e][pxl];
      *(bf16x8*)(xh + (long)(r * 130 + col0 + pxl) * 512 + c0 + oct * 8) = v;
    }
  }
}

// ---------------- conv1 implicit GEMM: in-group pipelined fragments --------
// R5 post-mortem: barrier density was NOT the serializer (9/superslot vs
// 3/superslot both ~1400cy/subslot). Convoy effect: 8 phase-locked waves
// all read (LDS pipe 64xds_read_b128 = ~770cy/CU), all wait, all MFMA
// (~620cy/CU) -> serial sum ~1390cy. Fix = intra-wave ILP: issue subslot
// t+1's ds_reads before subslot t's MFMA cluster, within the group whose
// data is already certified at the group barrier (A via WAITA3, B via
// superslot WAIT0 -- safety identical to R5). Affordable now: R5 base is
// 60 arch VGPRs, +1 fragment set (X/Y alternation, no copies) ~= +32.
// Pipeline per group: R0,R1 | M0 | R2 | M1 | M2 with sched_barrier pins.
// Expected group: ~200 (R0 latency) + max(LDS 2300, MFMA 1860) + barrier
// ~= 2700cy vs R5's 4350.
__global__ __launch_bounds__(512, 1) void conv1_gemm(
    const bf16* __restrict__ w1t, const bf16* __restrict__ xh,
    const float* __restrict__ b1, bf16* __restrict__ mid) {
  extern __shared__ char smem[];
  // B ping [784 rows][64B] @ 0 ; B pong @ 50176 ; A taps 9x4KB @ 100352
  char* Bb0 = smem;
  char* Bb1 = smem + 50176;
  char* Ab  = smem + 100352;          // total 137216 B

  const int tid  = threadIdx.x;
  const int wave = tid >> 6;
  const int lane = tid & 63;
  const int quad = lane >> 4;
  const int l15  = lane & 15;
  const int b    = blockIdx.x;
  const int ocT  = b & 7;          // XCD-affine: same ocT -> same XCD L2
  const int r4   = b >> 3;         // 4-image-row px tile, 0..31
  const long rbase = (long)r4 * 520;        // 4*130 xh rows per tile

  const char* w1tB = (const char*)w1t + (long)ocT * 65536;
  const char* xhB  = (const char*)xh;

  const int srow = lane >> 2;                               // 16 rows/unit
  const int schk = ((lane & 3) ^ ((lane >> 3) & 3)) << 4;   // src chunk swizzle

  // stage the 4KB A tile of (tap j, col ck) into slot j; waves 0-3 do 1KB each
  auto stageA = [&](int ck, int j) {
    const char* src = w1tB + (long)j * 524288 +
                      (long)(wave * 16 + srow) * 1024 + ck * 64 + schk;
    gload16(src, Ab + j * 4096 + wave * 1024);
  };
  // stage 1KB unit u (16 xh rows) of the B window at column ck
  auto stageB = [&](int ck, int u, char* Bt) {
    const char* src = xhB + (rbase + u * 16 + srow) * 1024 + ck * 64 + schk;
    gload16(src, Bt + u * 1024);
  };

  // per-wave B row bases: px p = wave*64 + ni*16 + l15 ->
  // local row = (p>>7)*130 + (p&127) + l15  (+ ky*130 + kx at use)
  const int p0 = wave * 64;
  const int rowb0 = (((p0 + 0)  >> 7) * 130) + ((p0 + 0)  & 127) + l15;
  const int rowb1 = (((p0 + 16) >> 7) * 130) + ((p0 + 16) & 127) + l15;
  const int rowb2 = (((p0 + 32) >> 7) * 130) + ((p0 + 32) & 127) + l15;
  const int rowb3 = (((p0 + 48) >> 7) * 130) + ((p0 + 48) & 127) + l15;
  const int aoff = l15 * 64 + ((quad ^ ((l15 >> 1) & 3)) << 4);

  f32x4 acc[4][4];
#pragma unroll
  for (int i = 0; i < 4; ++i)
#pragma unroll
    for (int k = 0; k < 4; ++k) acc[i][k] = (f32x4){0.f, 0.f, 0.f, 0.f};

  // two fragment sets (X/Y), individually named; subslots 0,2 use X, 1 uses Y
  bf16x8 xa0, xa1, xa2, xa3, xb0, xb1, xb2, xb3;
  bf16x8 ya0, ya1, ya2, ya3, yb0, yb1, yb2, yb3;

#define BROW(R, BT) (*(const bf16x8*)((BT) + (R) * 64 + ((quad ^ (((R) >> 1) & 3)) << 4)))
#define READSET(A0, A1, A2, A3, B0, B1, B2, B3, AB, R0, R1, R2, R3, BT)       \
  do {                                                                        \
    A0 = *(const bf16x8*)((AB));                                              \
    A1 = *(const bf16x8*)((AB) + 1024);                                       \
    A2 = *(const bf16x8*)((AB) + 2048);                                       \
    A3 = *(const bf16x8*)((AB) + 3072);                                       \
    B0 = BROW((R0), BT); B1 = BROW((R1), BT);                                 \
    B2 = BROW((R2), BT); B3 = BROW((R3), BT);                                 \
  } while (0)
#define MF(MI, NI, AF, BF)                                                    \
  acc[MI][NI] = __builtin_amdgcn_mfma_f32_16x16x32_bf16(AF, BF, acc[MI][NI], 0, 0, 0)
#define MFMASET(A0, A1, A2, A3, B0, B1, B2, B3)                               \
  do {                                                                        \
    __builtin_amdgcn_s_setprio(1);                                            \
    MF(0, 0, A0, B0); MF(0, 1, A0, B1); MF(0, 2, A0, B2); MF(0, 3, A0, B3);   \
    MF(1, 0, A1, B0); MF(1, 1, A1, B1); MF(1, 2, A1, B2); MF(1, 3, A1, B3);   \
    MF(2, 0, A2, B0); MF(2, 1, A2, B1); MF(2, 2, A2, B2); MF(2, 3, A2, B3);   \
    MF(3, 0, A3, B0); MF(3, 1, A3, B1); MF(3, 2, A3, B2); MF(3, 3, A3, B3);   \
    __builtin_amdgcn_s_setprio(0);                                            \
  } while (0)
#define GROUP_PIPE(BT)                                                        \
  do {                                                                        \
    const char* abq = Ab + q * 12288 + aoff;                                  \
    const int rq0 = rowb0 + q * 130;                                          \
    const int rq1 = rowb1 + q * 130;                                          \
    const int rq2 = rowb2 + q * 130;                                          \
    const int rq3 = rowb3 + q * 130;                                          \
    READSET(xa0, xa1, xa2, xa3, xb0, xb1, xb2, xb3, abq,                      \
            rq0, rq1, rq2, rq3, BT);                                          \
    READSET(ya0, ya1, ya2, ya3, yb0, yb1, yb2, yb3, abq + 4096,               \
            rq0 + 1, rq1 + 1, rq2 + 1, rq3 + 1, BT);                          \
    __builtin_amdgcn_sched_barrier(0);                                        \
    MFMASET(xa0, xa1, xa2, xa3, xb0, xb1, xb2, xb3);                          \
    READSET(xa0, xa1, xa2, xa3, xb0, xb1, xb2, xb3, abq + 8192,               \
            rq0 + 2, rq1 + 2, rq2 + 2, rq3 + 2, BT);                          \
    __builtin_amdgcn_sched_barrier(0);                                        \
    MFMASET(ya0, ya1, ya2, ya3, yb0, yb1, yb2, yb3);                          \
    MFMASET(xa0, xa1, xa2, xa3, xb0, xb1, xb2, xb3);                          \
  } while (0)

#define WAITA3 asm volatile("s_waitcnt vmcnt(3)" ::: "memory")
#define WAIT0  asm volatile("s_waitcnt vmcnt(0)" ::: "memory")
#define BARR   __builtin_amdgcn_s_barrier()

  // prologue: B(0) fully; A taps 0-5 of ck=0 (groups 0 and 1's tiles)
  if (wave < 4) {
    stageA(0, 0); stageA(0, 1); stageA(0, 2);
    stageA(0, 3); stageA(0, 4); stageA(0, 5);
  } else {
    const int u0 = (wave == 4) ? 0 : 13 + (wave - 5) * 12;
    const int n  = (wave == 4) ? 13 : 12;
    for (int u = 0; u < n; ++u) stageB(0, u0 + u, Bb0);
  }

  // 48 groups of 3 subslots; group g: superslot s = g/3, phase q = g%3
  int s = 0, q = 0;
#pragma unroll 1
  for (int g = 0; g < 47; ++g) {
    if (wave < 4) { WAITA3; }           // drain oldest A batch (this group's)
    else if (q == 0) { WAIT0; }         // superslot boundary: pong landed
    BARR;
    char* Bcur = (s & 1) ? Bb1 : Bb0;
    char* Bnxt = (s & 1) ? Bb0 : Bb1;
    if (g <= 45) {
      if (wave < 4) {                   // stage group g+2's 3 A taps
        const int qs = (q + 2 >= 3) ? q - 1 : q + 2;   // (q+2)%3
        const int ss = s + (q >= 1 ? 1 : 0);
        stageA(ss, qs * 3); stageA(ss, qs * 3 + 1); stageA(ss, qs * 3 + 2);
      } else if (g <= 44) {             // stage ~1/3 of B(s+1)
        int n, uoff;
        if (wave == 4) { n = (q == 0) ? 5 : 4; uoff = (q == 0) ? 0 : (q == 1 ? 5 : 9); }
        else           { n = 4; uoff = 13 + (wave - 5) * 12 + q * 4; }
        for (int u = 0; u < n; ++u) stageB(s + 1, uoff + u, Bnxt);
      }
    }
    GROUP_PIPE(Bcur);
    ++q; if (q == 3) { q = 0; ++s; }
  }
  { // g = 47 peel: s=15, q=2; drain last A batch fully
    if (wave < 4) { WAIT0; }
    BARR;
    char* Bcur = Bb1;
    GROUP_PIPE(Bcur);
  }

#undef WAITA3
#undef WAIT0
#undef BARR
#undef BROW
#undef READSET
#undef MF
#undef MFMASET
#undef GROUP_PIPE

  // epilogue: bias + relu, store bf16 NHWC mid[px][oc]
#pragma unroll
  for (int mi = 0; mi < 4; ++mi) {
    const int oc = ocT * 64 + mi * 16 + quad * 4;
    const float bv0 = b1[oc], bv1 = b1[oc + 1], bv2 = b1[oc + 2], bv3 = b1[oc + 3];
#pragma unroll
    for (int ni = 0; ni < 4; ++ni) {
      const int pb  = p0 + ni * 16;
      const int gpx = (r4 * 4 + (pb >> 7)) * 128 + (pb & 127) + l15;
      f32x4 a = acc[mi][ni];
      float t0 = a[0] + bv0; t0 = t0 > 0.f ? t0 : 0.f;
      float t1 = a[1] + bv1; t1 = t1 > 0.f ? t1 : 0.f;
      float t2 = a[2] + bv2; t2 = t2 > 0.f ? t2 : 0.f;
      float t3 = a[3] + bv3; t3 = t3 > 0.f ? t3 : 0.f;
      bf16x4 v = {(bf16)t0, (bf16)t1, (bf16)t2, (bf16)t3};
      *(bf16x4*)(mid + (long)gpx * 512 + oc) = v;
    }
  }
}

// ---------------- head: barrier-free K-split GEMM + anchor decode ----------
__global__ __launch_bounds__(256) void head_gemm(
    const bf16* __restrict__ w2p, const bf16* __restrict__ mid,
    const float* __restrict__ loc_b, const float* __restrict__ score_b,
    float* __restrict__ out) {
  __shared__ f32x4 red[3][64][5];
  const int tid  = threadIdx.x;
  const int wave = tid >> 6;
  const int lane = tid & 63;
  const int quad = lane >> 4;
  const int l15  = lane & 15;
  const int px0  = blockIdx.x * 16;
  const bf16* mB = mid + (long)px0 * 512;

  f32x4 acc[5];
#pragma unroll
  for (int i = 0; i < 5; ++i) acc[i] = (f32x4){0.f, 0.f, 0.f, 0.f};

#pragma unroll
  for (int st = 0; st < 4; ++st) {
    const int k0 = wave * 128 + st * 32;
    bf16x8 bfr = *(const bf16x8*)(mB + (long)l15 * 512 + k0 + quad * 8);
#pragma unroll
    for (int mi = 0; mi < 5; ++mi) {
      bf16x8 af = *(const bf16x8*)(w2p + (long)(mi * 16 + l15) * 512 + k0 + quad * 8);
      acc[mi] = __builtin_amdgcn_mfma_f32_16x16x32_bf16(af, bfr, acc[mi], 0, 0, 0);
    }
  }

  if (wave > 0) {
#pragma unroll
    for (int mi = 0; mi < 5; ++mi) red[wave - 1][lane][mi] = acc[mi];
  }
  __syncthreads();
  if (wave != 0) return;
#pragma unroll
  for (int w = 0; w < 3; ++w)
#pragma unroll
    for (int mi = 0; mi < 5; ++mi) acc[mi] += red[w][lane][mi];

  const int p    = px0 + l15;
  const int hh   = p >> 7;
  const int wcol = p & 127;
  const float cx = 16.f * (float)hh;
  const float cy = 16.f * (float)wcol;
  const float s0 = quad == 0 ? 45.f : quad == 1 ? 91.f : quad == 2 ? 181.f : 362.f;
  const float s1 = quad == 0 ? 32.f : quad == 1 ? 64.f : quad == 2 ? 128.f : 256.f;
  const float s2 = quad == 0 ? 23.f : quad == 1 ? 45.f : quad == 2 ? 91.f : 181.f;
  const float aw[3] = {s0, s1, s2};
  const float ah[3] = {s2, s1, s0};
#pragma unroll
  for (int mi = 0; mi < 5; ++mi) {
#pragma unroll
    for (int r = 0; r < 4; ++r) {
      const int oc2 = mi * 16 + quad * 4 + r;
      float v = acc[mi][r];
      if (mi < 3) {
        v += loc_b[oc2];
        out[p * 48 + oc2] = v;
        float roi;
        if (r == 0)      roi = v * aw[mi] + cx;
        else if (r == 1) roi = v * ah[mi] + cy;
        else if (r == 2) roi = __expf(v) * aw[mi];
        else             roi = __expf(v) * ah[mi];
        out[OUT_ROI + p * 48 + oc2] = roi;
      } else {
        const int sc = oc2 - 48;
        if (sc < 24) {
          v += score_b[sc];
          out[OUT_CLS + p * 24 + sc] = v;
        }
      }
    }
  }
}

// ---------------------------------------------------------------------------
extern "C" void kernel_launch(void* const* d_in, const int* in_sizes, int n_in,
                              void* d_out, int out_size, void* d_ws, size_t ws_size,
                              hipStream_t stream) {
  (void)in_sizes; (void)n_in; (void)out_size; (void)ws_size;
  const float* x       = (const float*)d_in[0];
  const float* conv1_w = (const float*)d_in[1];
  const float* conv1_b = (const float*)d_in[2];
  const float* score_w = (const float*)d_in[3];
  const float* score_b = (const float*)d_in[4];
  const float* loc_w   = (const float*)d_in[5];
  const float* loc_b   = (const float*)d_in[6];
  char* ws = (char*)d_ws;
  bf16* xh  = (bf16*)(ws + WS_XH);
  bf16* w1t = (bf16*)(ws + WS_W1T);
  bf16* w2p = (bf16*)(ws + WS_W2P);
  bf16* mid = (bf16*)(ws + WS_MID);
  float* out = (float*)d_out;

  static int attr_done = 0;
  if (!attr_done) {
    (void)hipFuncSetAttribute((const void*)conv1_gemm,
                              hipFuncAttributeMaxDynamicSharedMemorySize, 137216);
    attr_done = 1;
  }

  hipLaunchKernelGGL(prep_all,   dim3(3364), dim3(256), 0, stream,
                     (int4*)xh, conv1_w, w1t, loc_w, score_w, w2p, x, xh);
  hipLaunchKernelGGL(conv1_gemm, dim3(256),  dim3(512), 137216, stream,
                     w1t, xh, conv1_b, mid);
  hipLaunchKernelGGL(head_gemm,  dim3(1024), dim3(256), 0, stream,
                     w2p, mid, loc_b, score_b, out);
}

// Round 7
// 174.496 us; speedup vs baseline: 1.3679x; 1.0292x over previous
//
#include <hip/hip_runtime.h>

typedef __bf16 bf16;
typedef __attribute__((ext_vector_type(8))) __bf16 bf16x8;
typedef __attribute__((ext_vector_type(4))) __bf16 bf16x4;
typedef __attribute__((ext_vector_type(4))) float f32x4;

__device__ __forceinline__ void gload16(const void* g, void* l) {
  __builtin_amdgcn_global_load_lds(
      (__attribute__((address_space(1))) void*)(g),
      (__attribute__((address_space(3))) void*)(l), 16, 0, 0);
}

// ---------------------------------------------------------------------------
// Workspace layout (bytes):
//   xh  : NHWC padded input, bf16 [130][130][512]        = 17,305,600
//   w1t : conv1 weights,     bf16 [9][512 oc][512 c]     =  4,718,592
//   w2p : packed head wts,   bf16 [80 oc2][512 c]        =     81,920
//   mid : conv1 output NHWC, bf16 [16384 px][512 oc]     = 16,777,216
// ---------------------------------------------------------------------------
#define WS_XH   0
#define WS_W1T  17305600
#define WS_W2P  22024192
#define WS_MID  22106112

#define OUT_CLS 786432
#define OUT_ROI 1179648

// ---------------- fused prep: border | w1 repack | w2 pack | transpose -----
// grid = 132 + 1024 + 160 + 2048 = 3364 blocks, 256 thr    (unchanged)
__global__ void prep_all(int4* __restrict__ xh4,
                         const float* __restrict__ w1, bf16* __restrict__ w1t,
                         const float* __restrict__ loc_w,
                         const float* __restrict__ score_w,
                         bf16* __restrict__ w2p,
                         const float* __restrict__ x, bf16* __restrict__ xh) {
  __shared__ float lds[64][65];
  float* ldsf = &lds[0][0];
  const int t = threadIdx.x;
  const int b = blockIdx.x;
  if (b < 132) {                       // ---- xh halo border zeroing
    const int4 z = make_int4(0, 0, 0, 0);
    if (b < 130) {
      if (t < 64)       xh4[(b * 130 + 0) * 64 + t] = z;
      else if (t < 128) xh4[(b * 130 + 129) * 64 + (t - 64)] = z;
    } else {
      const int r = (b == 130) ? 0 : 129;
      for (int i = t; i < 8320; i += 256) xh4[r * 8320 + i] = z;
    }
  } else if (b < 1156) {               // ---- w1 [oc][c][3][3] -> w1t[j][oc][c]
    const int bb = b - 132;
    const long base = (long)bb * 2304;
#pragma unroll
    for (int i = 0; i < 9; ++i) ldsf[i * 256 + t] = w1[base + i * 256 + t];
    __syncthreads();
    const int pair0 = bb * 256;        // pair = oc*512 + c
#pragma unroll
    for (int j = 0; j < 9; ++j)
      w1t[(long)j * 262144 + pair0 + t] = (bf16)ldsf[t * 9 + j];
  } else if (b < 1316) {               // ---- pack loc_w+score_w -> w2p[80][512]
    const int idx = (b - 1156) * 256 + t;
    const int c  = idx & 511;
    const int oc = idx >> 9;
    float v = 0.f;
    if (oc < 48)      v = loc_w[oc * 512 + c];
    else if (oc < 72) v = score_w[(oc - 48) * 512 + c];
    w2p[idx] = (bf16)v;
  } else {                             // ---- NCHW fp32 -> NHWC bf16 transpose
    const int bb   = b - 1316;
    const int ct   = bb & 7;
    const int colt = (bb >> 3) & 1;
    const int r    = 1 + (bb >> 4);
    const int c0   = ct * 64;
    const int col0 = 1 + colt * 64;
    const int lcol = t & 63;
    const int coff = t >> 6;
#pragma unroll
    for (int i = 0; i < 16; ++i) {
      const int cl = coff + i * 4;
      lds[cl][lcol] = x[(long)(c0 + cl) * 16384 + (r - 1) * 128 + (col0 - 1) + lcol];
    }
    __syncthreads();
#pragma unroll
    for (int i = 0; i < 2; ++i) {
      const int idx = i * 256 + t;
      const int pxl = idx >> 3;
      const int oct = idx & 7;
      bf16x8 v;
#pragma unroll
      for (int e = 0; e < 8; ++e) v[e] = (bf16)lds[oct * 8 + e][pxl];
      *(bf16x8*)(xh + (long)(r * 130 + col0 + pxl) * 512 + c0 + oct * 8) = v;
    }
  }
}

// ---------------- conv1 implicit GEMM: wave-specialized, 128px waves -------
// R1/R5/R6 all pin subslot at ~1400cy = LDS content (770) + MFMA (620)
// SERIAL, invariant to barrier density and intra-wave prefetch: symmetric
// waves convoy at instruction granularity (2/SIMD hit lgkm together).
// This version:
//  * waves 0-3 = pure compute (64oc x 128px tile each, acc 4x8, NO vmcnt
//    waits ever); waves 4-7 = pure stagers (counted vmcnt(7)/vmcnt(3),
//    never 0 mid-loop, certify data at group barrier). 1 compute + 1
//    stager per SIMD -> no symmetric-partner convoy.
//  * 2x wave tile: 12 ds_reads per 32 MFMA (was 16/16) -> CU LDS content
//    580cy/subslot < MFMA 620cy -> MFMA-bound if overlap engages.
//  * half-subslot pipeline: reads for half h+1 (X/Y sets) issue before
//    MFMA(h); per half 16 MFMA (~310cy/SIMD) covers ~24 CU LDS reads.
// Staging/read swizzles, B window, A ring (9 taps), ping/pong, epilogue
// mapping all carried over unchanged from the verified R5 kernel.
// Ring safety: group g stages A(g+2) into slots of g-1 (reads done before
// barrier g); stager queue order B-then-A makes vmcnt(3) at q==0 certify
// the B pong, vmcnt(7) at q!=0 certify A(g). Regs: acc 128 + 16 frags 64
// + addr ~25 = ~215 < 256 cap (launch_bounds(512,1), proven R5/R6).
__global__ __launch_bounds__(512, 1) void conv1_gemm(
    const bf16* __restrict__ w1t, const bf16* __restrict__ xh,
    const float* __restrict__ b1, bf16* __restrict__ mid) {
  extern __shared__ char smem[];
  // B ping [784 rows][64B] @ 0 ; B pong @ 50176 ; A taps 9x4KB @ 100352
  char* Bb0 = smem;
  char* Bb1 = smem + 50176;
  char* Ab  = smem + 100352;          // total 137216 B

  const int tid  = threadIdx.x;
  const int wave = tid >> 6;
  const int lane = tid & 63;
  const int quad = lane >> 4;
  const int l15  = lane & 15;
  const int b    = blockIdx.x;
  const int ocT  = b & 7;          // XCD-affine: same ocT -> same XCD L2
  const int r4   = b >> 3;         // 4-image-row px tile, 0..31
  const long rbase = (long)r4 * 520;        // 4*130 xh rows per tile

  const char* w1tB = (const char*)w1t + (long)ocT * 65536;
  const char* xhB  = (const char*)xh;

  const int srow = lane >> 2;                               // 16 rows/unit
  const int schk = ((lane & 3) ^ ((lane >> 3) & 3)) << 4;   // src chunk swizzle
  const int si   = wave - 4;                                // stager idx 0..3

  // stage the 4KB A tile of (tap j, col ck): stager si writes rows si*16..+15
  auto stageA = [&](int ck, int j) {
    const char* src = w1tB + (long)j * 524288 +
                      (long)(si * 16 + srow) * 1024 + ck * 64 + schk;
    gload16(src, Ab + j * 4096 + si * 1024);
  };
  // stage 1KB unit u (16 xh rows) of the B window at column ck
  auto stageB = [&](int ck, int u, char* Bt) {
    const char* src = xhB + (rbase + u * 16 + srow) * 1024 + ck * 64 + schk;
    gload16(src, Bt + u * 1024);
  };

  // compute wave cw owns px [cw*128, cw*128+128): local B row base
  const int cw    = wave;                 // valid for waves 0-3
  const int cwrow = cw * 130 + l15;
  const int aoff  = l15 * 64 + ((quad ^ ((l15 >> 1) & 3)) << 4);

  f32x4 acc[4][8];
#pragma unroll
  for (int i = 0; i < 4; ++i)
#pragma unroll
    for (int k = 0; k < 8; ++k) acc[i][k] = (f32x4){0.f, 0.f, 0.f, 0.f};

  // X/Y fragment sets: A per subslot, B per half-subslot
  bf16x8 ax0, ax1, ax2, ax3, ay0, ay1, ay2, ay3;
  bf16x8 bx0, bx1, bx2, bx3, by0, by1, by2, by3;

#define BROW(R, BT) (*(const bf16x8*)((BT) + (R) * 64 + ((quad ^ (((R) >> 1) & 3)) << 4)))
#define READ_A(A0, A1, A2, A3, TAP)                                           \
  do {                                                                        \
    const char* _ab = Ab + (TAP) * 4096 + aoff;                               \
    A0 = *(const bf16x8*)(_ab);                                               \
    A1 = *(const bf16x8*)(_ab + 1024);                                        \
    A2 = *(const bf16x8*)(_ab + 2048);                                        \
    A3 = *(const bf16x8*)(_ab + 3072);                                        \
  } while (0)
#define READ_B(B0, B1, B2, B3, KO, HOFF, BT)                                  \
  do {                                                                        \
    const int _r0 = cwrow + (HOFF) + (KO);                                    \
    B0 = BROW(_r0, BT);                                                       \
    B1 = BROW(_r0 + 16, BT);                                                  \
    B2 = BROW(_r0 + 32, BT);                                                  \
    B3 = BROW(_r0 + 48, BT);                                                  \
  } while (0)
#define MF2(MI, CJ, AF, BF)                                                   \
  acc[MI][CJ] = __builtin_amdgcn_mfma_f32_16x16x32_bf16(AF, BF, acc[MI][CJ], 0, 0, 0)
#define MFMAH(A0, A1, A2, A3, B0, B1, B2, B3, C)                              \
  do {                                                                        \
    __builtin_amdgcn_s_setprio(1);                                            \
    MF2(0, (C) + 0, A0, B0); MF2(0, (C) + 1, A0, B1);                         \
    MF2(0, (C) + 2, A0, B2); MF2(0, (C) + 3, A0, B3);                         \
    MF2(1, (C) + 0, A1, B0); MF2(1, (C) + 1, A1, B1);                         \
    MF2(1, (C) + 2, A1, B2); MF2(1, (C) + 3, A1, B3);                         \
    MF2(2, (C) + 0, A2, B0); MF2(2, (C) + 1, A2, B1);                         \
    MF2(2, (C) + 2, A2, B2); MF2(2, (C) + 3, A2, B3);                         \
    MF2(3, (C) + 0, A3, B0); MF2(3, (C) + 1, A3, B1);                         \
    MF2(3, (C) + 2, A3, B2); MF2(3, (C) + 3, A3, B3);                         \
    __builtin_amdgcn_s_setprio(0);                                            \
  } while (0)

#define WAIT0  asm volatile("s_waitcnt vmcnt(0)" ::: "memory")
#define WAIT3  asm volatile("s_waitcnt vmcnt(3)" ::: "memory")
#define WAIT7  asm volatile("s_waitcnt vmcnt(7)" ::: "memory")
#define BARR   __builtin_amdgcn_s_barrier()
#define SB     __builtin_amdgcn_sched_barrier(0)

  // prologue: stagers load B(0) fully + A taps 0-5 of ck0 (groups 0,1)
  if (wave >= 4) {
    const int u0 = (si == 0) ? 0 : 13 + (si - 1) * 12;
    const int n  = (si == 0) ? 13 : 12;
    for (int u = 0; u < n; ++u) stageB(0, u0 + u, Bb0);
#pragma unroll
    for (int j = 0; j < 6; ++j) stageA(0, j);
  }

  // 48 groups of 3 subslots; group g = (s, q): taps q*3..q*3+2 of ck s
  int s = 0, q = 0;
#pragma unroll 1
  for (int g = 0; g < 48; ++g) {
    if (wave >= 4) {
      if (g == 0 || g == 47) { WAIT0; }
      else if (q == 0 || g == 46) { WAIT3; }
      else { WAIT7; }
    }
    BARR;
    char* Bcur = (s & 1) ? Bb1 : Bb0;
    char* Bnxt = (s & 1) ? Bb0 : Bb1;
    if (wave >= 4) {
      // B first, then A (queue order makes the counted waits certify right)
      if (s < 15) {
        const int n  = (si == 0 && q == 0) ? 5 : 4;
        const int u0 = (si == 0) ? ((q == 0) ? 0 : 5 + (q - 1) * 4)
                                 : (13 + (si - 1) * 12 + q * 4);
        for (int u = 0; u < n; ++u) stageB(s + 1, u0 + u, Bnxt);
      }
      if (g <= 45) {                    // stage A(g+2): 3 taps, 1KB each
        const int ss = s + ((q >= 1) ? 1 : 0);
        const int jb = ((q + 2) % 3) * 3;
        stageA(ss, jb); stageA(ss, jb + 1); stageA(ss, jb + 2);
      }
    } else {
      // ---- compute group: 3 subslots x 2 halves, 1-deep read pipeline ----
      const int j0 = q * 3;
      const int kb = q * 130;
      READ_A(ax0, ax1, ax2, ax3, j0);
      READ_B(bx0, bx1, bx2, bx3, kb, 0, Bcur);
      SB;
      READ_B(by0, by1, by2, by3, kb, 64, Bcur);
      SB;
      MFMAH(ax0, ax1, ax2, ax3, bx0, bx1, bx2, bx3, 0);
      READ_A(ay0, ay1, ay2, ay3, j0 + 1);
      READ_B(bx0, bx1, bx2, bx3, kb + 1, 0, Bcur);
      SB;
      MFMAH(ax0, ax1, ax2, ax3, by0, by1, by2, by3, 4);
      READ_B(by0, by1, by2, by3, kb + 1, 64, Bcur);
      SB;
      MFMAH(ay0, ay1, ay2, ay3, bx0, bx1, bx2, bx3, 0);
      READ_A(ax0, ax1, ax2, ax3, j0 + 2);
      READ_B(bx0, bx1, bx2, bx3, kb + 2, 0, Bcur);
      SB;
      MFMAH(ay0, ay1, ay2, ay3, by0, by1, by2, by3, 4);
      READ_B(by0, by1, by2, by3, kb + 2, 64, Bcur);
      SB;
      MFMAH(ax0, ax1, ax2, ax3, bx0, bx1, bx2, bx3, 0);
      MFMAH(ax0, ax1, ax2, ax3, by0, by1, by2, by3, 4);
    }
    ++q; if (q == 3) { q = 0; ++s; }
  }

#undef WAIT0
#undef WAIT3
#undef WAIT7
#undef BARR
#undef SB
#undef BROW
#undef READ_A
#undef READ_B
#undef MF2
#undef MFMAH

  if (wave >= 4) return;               // stagers done

  // epilogue: bias + relu, store bf16 NHWC mid[px][oc]
#pragma unroll
  for (int mi = 0; mi < 4; ++mi) {
    const int oc = ocT * 64 + mi * 16 + quad * 4;
    const float bv0 = b1[oc], bv1 = b1[oc + 1], bv2 = b1[oc + 2], bv3 = b1[oc + 3];
#pragma unroll
    for (int ni = 0; ni < 8; ++ni) {
      const int gpx = (r4 * 4 + cw) * 128 + ni * 16 + l15;
      f32x4 a = acc[mi][ni];
      float t0 = a[0] + bv0; t0 = t0 > 0.f ? t0 : 0.f;
      float t1 = a[1] + bv1; t1 = t1 > 0.f ? t1 : 0.f;
      float t2 = a[2] + bv2; t2 = t2 > 0.f ? t2 : 0.f;
      float t3 = a[3] + bv3; t3 = t3 > 0.f ? t3 : 0.f;
      bf16x4 v = {(bf16)t0, (bf16)t1, (bf16)t2, (bf16)t3};
      *(bf16x4*)(mid + (long)gpx * 512 + oc) = v;
    }
  }
}

// ---------------- head: barrier-free K-split GEMM + anchor decode ----------
__global__ __launch_bounds__(256) void head_gemm(
    const bf16* __restrict__ w2p, const bf16* __restrict__ mid,
    const float* __restrict__ loc_b, const float* __restrict__ score_b,
    float* __restrict__ out) {
  __shared__ f32x4 red[3][64][5];
  const int tid  = threadIdx.x;
  const int wave = tid >> 6;
  const int lane = tid & 63;
  const int quad = lane >> 4;
  const int l15  = lane & 15;
  const int px0  = blockIdx.x * 16;
  const bf16* mB = mid + (long)px0 * 512;

  f32x4 acc[5];
#pragma unroll
  for (int i = 0; i < 5; ++i) acc[i] = (f32x4){0.f, 0.f, 0.f, 0.f};

#pragma unroll
  for (int st = 0; st < 4; ++st) {
    const int k0 = wave * 128 + st * 32;
    bf16x8 bfr = *(const bf16x8*)(mB + (long)l15 * 512 + k0 + quad * 8);
#pragma unroll
    for (int mi = 0; mi < 5; ++mi) {
      bf16x8 af = *(const bf16x8*)(w2p + (long)(mi * 16 + l15) * 512 + k0 + quad * 8);
      acc[mi] = __builtin_amdgcn_mfma_f32_16x16x32_bf16(af, bfr, acc[mi], 0, 0, 0);
    }
  }

  if (wave > 0) {
#pragma unroll
    for (int mi = 0; mi < 5; ++mi) red[wave - 1][lane][mi] = acc[mi];
  }
  __syncthreads();
  if (wave != 0) return;
#pragma unroll
  for (int w = 0; w < 3; ++w)
#pragma unroll
    for (int mi = 0; mi < 5; ++mi) acc[mi] += red[w][lane][mi];

  const int p    = px0 + l15;
  const int hh   = p >> 7;
  const int wcol = p & 127;
  const float cx = 16.f * (float)hh;
  const float cy = 16.f * (float)wcol;
  const float s0 = quad == 0 ? 45.f : quad == 1 ? 91.f : quad == 2 ? 181.f : 362.f;
  const float s1 = quad == 0 ? 32.f : quad == 1 ? 64.f : quad == 2 ? 128.f : 256.f;
  const float s2 = quad == 0 ? 23.f : quad == 1 ? 45.f : quad == 2 ? 91.f : 181.f;
  const float aw[3] = {s0, s1, s2};
  const float ah[3] = {s2, s1, s0};
#pragma unroll
  for (int mi = 0; mi < 5; ++mi) {
#pragma unroll
    for (int r = 0; r < 4; ++r) {
      const int oc2 = mi * 16 + quad * 4 + r;
      float v = acc[mi][r];
      if (mi < 3) {
        v += loc_b[oc2];
        out[p * 48 + oc2] = v;
        float roi;
        if (r == 0)      roi = v * aw[mi] + cx;
        else if (r == 1) roi = v * ah[mi] + cy;
        else if (r == 2) roi = __expf(v) * aw[mi];
        else             roi = __expf(v) * ah[mi];
        out[OUT_ROI + p * 48 + oc2] = roi;
      } else {
        const int sc = oc2 - 48;
        if (sc < 24) {
          v += score_b[sc];
          out[OUT_CLS + p * 24 + sc] = v;
        }
      }
    }
  }
}

// ---------------------------------------------------------------------------
extern "C" void kernel_launch(void* const* d_in, const int* in_sizes, int n_in,
                              void* d_out, int out_size, void* d_ws, size_t ws_size,
                              hipStream_t stream) {
  (void)in_sizes; (void)n_in; (void)out_size; (void)ws_size;
  const float* x       = (const float*)d_in[0];
  const float* conv1_w = (const float*)d_in[1];
  const float* conv1_b = (const float*)d_in[2];
  const float* score_w = (const float*)d_in[3];
  const float* score_b = (const float*)d_in[4];
  const float* loc_w   = (const float*)d_in[5];
  const float* loc_b   = (const float*)d_in[6];
  char* ws = (char*)d_ws;
  bf16* xh  = (bf16*)(ws + WS_XH);
  bf16* w1t = (bf16*)(ws + WS_W1T);
  bf16* w2p = (bf16*)(ws + WS_W2P);
  bf16* mid = (bf16*)(ws + WS_MID);
  float* out = (float*)d_out;

  static int attr_done = 0;
  if (!attr_done) {
    (void)hipFuncSetAttribute((const void*)conv1_gemm,
                              hipFuncAttributeMaxDynamicSharedMemorySize, 137216);
    attr_done = 1;
  }

  hipLaunchKernelGGL(prep_all,   dim3(3364), dim3(256), 0, stream,
                     (int4*)xh, conv1_w, w1t, loc_w, score_w, w2p, x, xh);
  hipLaunchKernelGGL(conv1_gemm, dim3(256),  dim3(512), 137216, stream,
                     w1t, xh, conv1_b, mid);
  hipLaunchKernelGGL(head_gemm,  dim3(1024), dim3(256), 0, stream,
                     w2p, mid, loc_b, score_b, out);
}